// Round 1
// baseline (3090.732 us; speedup 1.0000x reference)
//
#include <hip/hip_runtime.h>
#include <cmath>
#include <complex>
#include <algorithm>

// ---------------------------------------------------------------------------
// Problem constants: LMAX=2, NC=9, H=8, DQK=32, CV=16, K=8, U=25, N=2048, C=256
// ---------------------------------------------------------------------------

// ========================= host-side constant tables ========================
namespace {

using cd = std::complex<double>;

static double fct(int n) { double r = 1.0; for (int i = 2; i <= n; ++i) r *= i; return r; }

static double cg_coef(int j1, int m1, int j2, int m2, int j, int m) {
    if (m1 + m2 != m || j < std::abs(j1 - j2) || j > j1 + j2) return 0.0;
    double pref = std::sqrt((2 * j + 1) * fct(j + j1 - j2) * fct(j - j1 + j2) * fct(j1 + j2 - j) / fct(j1 + j2 + j + 1));
    pref *= std::sqrt(fct(j + m) * fct(j - m) * fct(j1 - m1) * fct(j1 + m1) * fct(j2 - m2) * fct(j2 + m2));
    double s = 0.0;
    for (int k = 0; k <= j1 + j2 - j; ++k) {
        int d0 = k, d1 = j1 + j2 - j - k, d2 = j1 - m1 - k, d3 = j2 + m2 - k, d4 = j - j2 + m1 + k, d5 = j - j1 - m2 + k;
        if (d0 < 0 || d1 < 0 || d2 < 0 || d3 < 0 || d4 < 0 || d5 < 0) continue;
        s += ((k & 1) ? -1.0 : 1.0) / (fct(d0) * fct(d1) * fct(d2) * fct(d3) * fct(d4) * fct(d5));
    }
    return pref * s;
}

static void umat(int l, cd u[5][5]) {
    for (int i = 0; i < 5; i++) for (int j = 0; j < 5; j++) u[i][j] = cd(0, 0);
    const double s = 1.0 / std::sqrt(2.0);
    for (int m = -l; m <= l; m++) {
        double sgn = (std::abs(m) & 1) ? -1.0 : 1.0;   // (-1)^m
        if (m > 0)      { u[l + m][l + m] = cd(sgn * s, 0); u[l + m][l - m] = cd(s, 0); }
        else if (m == 0){ u[l][l] = cd(1, 0); }
        else            { u[l + m][l + m] = cd(0, s);       u[l + m][l - m] = cd(0, -sgn * s); }
    }
}

static void real_cg_f(int l1, int l2, int L, double out[5][5][5]) {
    cd U1[5][5], U2[5][5], UL[5][5];
    umat(l1, U1); umat(l2, U2); umat(L, UL);
    const int n1 = 2 * l1 + 1, n2 = 2 * l2 + 1, n3 = 2 * L + 1;
    double cgt[5][5][5];
    for (int i1 = 0; i1 < n1; i1++) for (int i2 = 0; i2 < n2; i2++) for (int i3 = 0; i3 < n3; i3++)
        cgt[i1][i2][i3] = cg_coef(l1, i1 - l1, l2, i2 - l2, L, i3 - L);
    cd r[5][5][5];
    double nr = 0, ni = 0;
    for (int a1 = 0; a1 < n1; a1++) for (int b = 0; b < n2; b++) for (int c = 0; c < n3; c++) {
        cd acc(0, 0);
        for (int uu = 0; uu < n1; uu++) for (int vv = 0; vv < n2; vv++) for (int w = 0; w < n3; w++) {
            double cval = cgt[uu][vv][w];
            if (cval == 0.0) continue;
            acc += U1[a1][uu] * U2[b][vv] * std::conj(UL[c][w]) * cval;
        }
        r[a1][b][c] = acc;
        nr += acc.real() * acc.real();
        ni += acc.imag() * acc.imag();
    }
    const bool useRe = std::sqrt(nr) >= std::sqrt(ni);
    for (int a1 = 0; a1 < n1; a1++) for (int b = 0; b < n2; b++) for (int c = 0; c < n3; c++)
        out[a1][b][c] = useRe ? r[a1][b][c].real() : r[a1][b][c].imag();
}

// device constant buffer layout: YW[9*25] | RRED[9*81] | DIRS[25*3]  = 1029 floats
static float  h_const[1029];
static float* d_const_g = nullptr;

struct GlobalInit {
    GlobalInit() {
        const double PI = 3.14159265358979323846;
        // Gauss-Legendre n=5 (ascending, numpy order)
        const double gx[5] = {-0.9061798459386640, -0.5384693101056831, 0.0, 0.5384693101056831, 0.9061798459386640};
        const double gw[5] = { 0.23692688505618908, 0.47862867049936647, 0.5688888888888889, 0.47862867049936647, 0.23692688505618908};
        double YW[9][25], DIRS[25][3];
        for (int u = 0; u < 25; ++u) {
            const int it = u / 5, ip = u % 5;
            const double ct = gx[it], wq = gw[it] * (2.0 * PI / 5.0), ph = 2.0 * PI * ip / 5.0;
            const double st = std::sqrt(std::max(1.0 - ct * ct, 0.0));
            const double x = st * std::cos(ph), y = st * std::sin(ph), z = ct;
            DIRS[u][0] = x; DIRS[u][1] = y; DIRS[u][2] = z;
            double Y[9];
            Y[0] = 0.282095;           Y[1] = 0.488603 * y;      Y[2] = 0.488603 * z;
            Y[3] = 0.488603 * x;       Y[4] = 1.092548 * x * y;  Y[5] = 1.092548 * y * z;
            Y[6] = 0.315392 * (3 * z * z - 1); Y[7] = 1.092548 * x * z; Y[8] = 0.546274 * (x * x - y * y);
            for (int e = 0; e < 9; e++) YW[e][u] = Y[e] * wq;
        }
        // right-reduced real CG
        double RRED[9][9][9];
        for (int i = 0; i < 9; i++) for (int j = 0; j < 9; j++) for (int k = 0; k < 9; k++) RRED[i][j][k] = 0.0;
        const int off[3] = {0, 1, 4};
        double cnt[3] = {0, 0, 0};
        double rc[5][5][5];
        for (int l1 = 0; l1 <= 2; l1++) for (int l2 = 0; l2 <= 2; l2++) {
            const int Llo = std::abs(l1 - l2), Lhi = std::min(l1 + l2, 2);
            for (int L = Llo; L <= Lhi; L++) {
                real_cg_f(l1, l2, L, rc);
                for (int i1 = 0; i1 < 2 * l1 + 1; i1++)
                    for (int i2 = 0; i2 < 2 * l2 + 1; i2++)
                        for (int i3 = 0; i3 < 2 * L + 1; i3++)
                            RRED[off[l1] + i1][off[l2] + i2][off[L] + i3] += rc[i1][i2][i3];
                cnt[L] += 1.0;
            }
        }
        for (int L = 0; L <= 2; L++) {
            const double dv = std::max(cnt[L], 1.0);
            for (int a1 = 0; a1 < 9; a1++) for (int b = 0; b < 9; b++)
                for (int k = 0; k < 2 * L + 1; k++) RRED[a1][b][off[L] + k] /= dv;
        }
        // pack
        for (int e = 0; e < 9; e++) for (int u = 0; u < 25; u++) h_const[e * 25 + u] = (float)YW[e][u];
        for (int e = 0; e < 9; e++) for (int l = 0; l < 9; l++) for (int m = 0; m < 9; m++)
            h_const[225 + e * 81 + l * 9 + m] = (float)RRED[e][l][m];
        for (int u = 0; u < 25; u++) for (int ax = 0; ax < 3; ax++) h_const[954 + u * 3 + ax] = (float)DIRS[u][ax];
        // one-time device alloc+copy at library load (outside kernel_launch/graph capture)
        if (hipMalloc((void**)&d_const_g, 1029 * sizeof(float)) == hipSuccess)
            hipMemcpy(d_const_g, h_const, 1029 * sizeof(float), hipMemcpyHostToDevice);
    }
} g_init;

} // namespace

// ============================== device kernels ==============================

// R[n][p][c]: p=0 -> feat(l=0); p=1 -> |l=1 block|; p=2 -> |l=2 block|
__global__ void radial_k(const float* __restrict__ feat, float* __restrict__ R) {
    const int n = blockIdx.x, c = threadIdx.x;
    const float* f = feat + (size_t)n * 9 * 256 + c;
    const float f0 = f[0];
    const float a1 = f[256], a2 = f[512], a3 = f[768];
    const float b1 = f[1024], b2 = f[1280], b3 = f[1536], b4 = f[1792], b5 = f[2048];
    const float r1 = sqrtf(a1 * a1 + a2 * a2 + a3 * a3 + 1e-8f);
    const float r2 = sqrtf(b1 * b1 + b2 * b2 + b3 * b3 + b4 * b4 + b5 * b5 + 1e-8f);
    float* o = R + (size_t)n * 768 + c;
    o[0] = f0; o[256] = r1; o[512] = r2;
}

// generic 64x64-tile f32 GEMM, C = A(MxK) @ B(KxN); mode 0 plain, 1 elu+1, 2 v-scatter
__global__ __launch_bounds__(256) void gemm_k(const float* __restrict__ A, const float* __restrict__ B,
                                              float* __restrict__ Cv, int M, int N, int Kd, int mode) {
    __shared__ float As[32][68];   // [k][row]
    __shared__ float Bs[32][68];   // [k][col]
    const int tid = threadIdx.x;
    const int tx = tid & 15, ty = tid >> 4;
    const int rb = blockIdx.y * 64, cb = blockIdx.x * 64;
    float acc[4][4];
#pragma unroll
    for (int i = 0; i < 4; i++) for (int j = 0; j < 4; j++) acc[i][j] = 0.f;
    for (int k0 = 0; k0 < Kd; k0 += 32) {
        __syncthreads();
#pragma unroll
        for (int i = 0; i < 2; i++) {
            const int idx = tid + i * 256;
            const int row = idx >> 3, kq = idx & 7;
            const float4 av = *(const float4*)(A + (size_t)(rb + row) * Kd + k0 + kq * 4);
            As[kq * 4 + 0][row] = av.x; As[kq * 4 + 1][row] = av.y;
            As[kq * 4 + 2][row] = av.z; As[kq * 4 + 3][row] = av.w;
        }
#pragma unroll
        for (int i = 0; i < 2; i++) {
            const int idx = tid + i * 256;
            const int kr = idx >> 4, cq = idx & 15;
            *(float4*)&Bs[kr][cq * 4] = *(const float4*)(B + (size_t)(k0 + kr) * N + cb + cq * 4);
        }
        __syncthreads();
#pragma unroll 8
        for (int k = 0; k < 32; k++) {
            const float4 a = *(const float4*)&As[k][ty * 4];
            const float4 b = *(const float4*)&Bs[k][tx * 4];
            const float av[4] = {a.x, a.y, a.z, a.w};
            const float bv[4] = {b.x, b.y, b.z, b.w};
#pragma unroll
            for (int i = 0; i < 4; i++)
#pragma unroll
                for (int j = 0; j < 4; j++) acc[i][j] += av[i] * bv[j];
        }
    }
#pragma unroll
    for (int i = 0; i < 4; i++) {
        const int r = rb + ty * 4 + i;
#pragma unroll
        for (int j = 0; j < 4; j++) {
            const int cc2 = cb + tx * 4 + j;
            float val = acc[i][j];
            if (mode == 1) val = (val > 0.f ? val : expf(val) - 1.f) + 1.f;
            if (mode == 2) {
                const int n = r / 9, l = r - n * 9, hq = cc2 >> 4, cvq = cc2 & 15;
                Cv[(((size_t)n * 8 + hq) * 16 + cvq) * 9 + l] = val;   // v[n][h][c][l]
            } else {
                Cv[(size_t)r * N + cc2] = val;
            }
        }
    }
}

// ck/sk[n][kk][u] = cos/sin(kappa_kk * pos_n . dir_u)
__global__ void trig_k(const float* __restrict__ pos, const float* __restrict__ kappa,
                       const float* __restrict__ cst, float* __restrict__ ck, float* __restrict__ sk) {
    const int n = blockIdx.x, t = threadIdx.x;
    if (t >= 200) return;
    const int kq = t / 25, u = t - kq * 25;
    const float* dirs = cst + 954;
    const float ph = kappa[kq] * (pos[n * 3] * dirs[u * 3] + pos[n * 3 + 1] * dirs[u * 3 + 1] + pos[n * 3 + 2] * dirs[u * 3 + 2]);
    float s, c;
    sincosf(ph, &s, &c);
    ck[(size_t)n * 200 + t] = c;
    sk[(size_t)n * 200 + t] = s;
}

__global__ void ksum_k(const float* __restrict__ kf, float* __restrict__ ksum) {
    const int j = threadIdx.x;   // 256
    float s0 = 0, s1 = 0, s2 = 0, s3 = 0;
    for (int n = 0; n < 2048; n += 4) {
        s0 += kf[(size_t)n * 256 + j];
        s1 += kf[(size_t)(n + 1) * 256 + j];
        s2 += kf[(size_t)(n + 2) * 256 + j];
        s3 += kf[(size_t)(n + 3) * 256 + j];
    }
    ksum[j] = s0 + s1 + s2 + s3;
}

__global__ void z_k(const float* __restrict__ qf, const float* __restrict__ ksum, float* __restrict__ Z) {
    const int idx = blockIdx.x * 256 + threadIdx.x;   // N*H = 16384
    const int n = idx >> 3, h = idx & 7;
    float s = 0.f;
#pragma unroll
    for (int d = 0; d < 32; d++) s += qf[(size_t)n * 256 + h * 32 + d] * ksum[h * 32 + d];
    Z[idx] = s + 1e-6f;
}

// G[kk][h][u][l*9+m] = sum_e aE[e,h,kk] * YW[e,u] * RRED[e,l,m]
__global__ void g_k(const float* __restrict__ a, const float* __restrict__ cst, float* __restrict__ G) {
    const int kk = blockIdx.x & 7, h = blockIdx.x >> 3;
    __shared__ float ae[9];
    if (threadIdx.x < 9) {
        const int ldeg[9] = {0, 1, 1, 1, 2, 2, 2, 2, 2};
        ae[threadIdx.x] = a[ldeg[threadIdx.x] * 64 + h * 8 + kk];
    }
    __syncthreads();
    const float* yw = cst;
    const float* rred = cst + 225;
    for (int i = threadIdx.x; i < 25 * 81; i += 256) {
        const int u = i / 81, lm = i - u * 81;
        float s = 0.f;
#pragma unroll
        for (int e = 0; e < 9; e++) s += ae[e] * yw[e * 25 + u] * rred[e * 81 + lm];
        G[((size_t)(kk * 8 + h) * 25 + u) * 81 + lm] = s;
    }
}

// M[(kk*25+u)*2+t][h][d][c*9+l] = sum_n trig[n,kk,u] * kf[n,h,d] * v[n,h,c,l]
__global__ __launch_bounds__(128) void multipole_k(const float* __restrict__ kf, const float* __restrict__ v,
                                                   const float* __restrict__ ckA, const float* __restrict__ skA,
                                                   float* __restrict__ Mv) {
    const int u = blockIdx.x, kk = blockIdx.y, h = blockIdx.z;
    const int tid = threadIdx.x;
    const int d = tid & 31, g = tid >> 5;   // g: 0..3, 36 cl each
    __shared__ float kf_s[16][32];
    __shared__ float v_s[16][144];
    __shared__ float c_s[16], s_s[16];
    float accC[36], accS[36];
#pragma unroll
    for (int i = 0; i < 36; i++) { accC[i] = 0.f; accS[i] = 0.f; }
    const int tb = kk * 25 + u;
    for (int nb = 0; nb < 2048; nb += 16) {
        __syncthreads();
        {
            const int n = tid >> 3, q = tid & 7;
            *(float4*)&kf_s[n][q * 4] = *(const float4*)(kf + (size_t)(nb + n) * 256 + h * 32 + q * 4);
        }
        for (int j = tid; j < 576; j += 128) {
            const int n = j / 36, q = j - n * 36;
            *(float4*)&v_s[n][q * 4] = *(const float4*)(v + ((size_t)(nb + n) * 8 + h) * 144 + q * 4);
        }
        if (tid < 16)       c_s[tid] = ckA[(size_t)(nb + tid) * 200 + tb];
        else if (tid < 32)  s_s[tid - 16] = skA[(size_t)(nb + tid - 16) * 200 + tb];
        __syncthreads();
#pragma unroll 4
        for (int n = 0; n < 16; n++) {
            const float kd = kf_s[n][d];
            const float ac = c_s[n] * kd, as_ = s_s[n] * kd;
#pragma unroll
            for (int i = 0; i < 9; i++) {
                const float4 vv = *(const float4*)&v_s[n][g * 36 + i * 4];
                accC[i * 4 + 0] += ac * vv.x; accC[i * 4 + 1] += ac * vv.y;
                accC[i * 4 + 2] += ac * vv.z; accC[i * 4 + 3] += ac * vv.w;
                accS[i * 4 + 0] += as_ * vv.x; accS[i * 4 + 1] += as_ * vv.y;
                accS[i * 4 + 2] += as_ * vv.z; accS[i * 4 + 3] += as_ * vv.w;
            }
        }
    }
    {
        float* dst = Mv + (((size_t)tb * 2 + 0) * 8 + h) * 4608 + d * 144 + g * 36;
#pragma unroll
        for (int i = 0; i < 9; i++)
            *(float4*)(dst + i * 4) = make_float4(accC[i * 4], accC[i * 4 + 1], accC[i * 4 + 2], accC[i * 4 + 3]);
    }
    {
        float* dst = Mv + (((size_t)tb * 2 + 1) * 8 + h) * 4608 + d * 144 + g * 36;
#pragma unroll
        for (int i = 0; i < 9; i++)
            *(float4*)(dst + i * 4) = make_float4(accS[i * 4], accS[i * 4 + 1], accS[i * 4 + 2], accS[i * 4 + 3]);
    }
}

// local/target stage: per (n,h): outm[c][m] = (1/Z) sum_{kk,u} [ ck*(qf.Mc) + sk*(qf.Ms) ] . G[l->m]
__global__ __launch_bounds__(512) void local_k(const float* __restrict__ qf,
                                               const float* __restrict__ ckA, const float* __restrict__ skA,
                                               const float* __restrict__ Mv, const float* __restrict__ G,
                                               const float* __restrict__ Z, float* __restrict__ outm) {
    const int nb = blockIdx.x * 64;   // 64 targets per block
    const int h = blockIdx.y;
    const int tid = threadIdx.x;      // 512
    const int c = tid & 15;
    const int g = tid >> 4;           // 0..31, 2 targets each
    __shared__ float qf_s[64][32];
    __shared__ float Mc_s[32][192];   // [d][c*12+l] (padded 9->12 for aligned float4)
    __shared__ float Ms_s[32][192];
    __shared__ float G_s[112];        // [l*12+m] padded
    {
        const int n = tid >> 3, q = tid & 7;
        *(float4*)&qf_s[n][q * 4] = *(const float4*)(qf + (size_t)(nb + n) * 256 + h * 32 + q * 4);
    }
    float om0[9], om1[9];
#pragma unroll
    for (int m = 0; m < 9; m++) { om0[m] = 0.f; om1[m] = 0.f; }
    const int n0 = nb + g * 2, n1 = n0 + 1;

    for (int kk = 0; kk < 8; kk++) {
        for (int u = 0; u < 25; u++) {
            __syncthreads();
            {
                const float* src  = Mv + (((size_t)(kk * 25 + u) * 2 + 0) * 8 + h) * 4608;
                const float* src2 = Mv + (((size_t)(kk * 25 + u) * 2 + 1) * 8 + h) * 4608;
                for (int j = tid; j < 4608; j += 512) {
                    const int d = j / 144, cl = j - d * 144;
                    const int ci = cl / 9, l = cl - ci * 9;
                    Mc_s[d][ci * 12 + l] = src[j];
                    Ms_s[d][ci * 12 + l] = src2[j];
                }
                if (tid < 81) G_s[(tid / 9) * 12 + (tid % 9)] = G[((size_t)(kk * 8 + h) * 25 + u) * 81 + tid];
            }
            __syncthreads();
            float Tc0[9], Tc1[9], Ts0[9], Ts1[9];
#pragma unroll
            for (int l = 0; l < 9; l++) { Tc0[l] = 0.f; Tc1[l] = 0.f; Ts0[l] = 0.f; Ts1[l] = 0.f; }
#pragma unroll 4
            for (int d = 0; d < 32; d++) {
                const float qa = qf_s[g * 2 + 0][d];
                const float qb = qf_s[g * 2 + 1][d];
                const float4 mca = *(const float4*)&Mc_s[d][c * 12];
                const float4 mcb = *(const float4*)&Mc_s[d][c * 12 + 4];
                const float  mcc = Mc_s[d][c * 12 + 8];
                const float4 msa = *(const float4*)&Ms_s[d][c * 12];
                const float4 msb = *(const float4*)&Ms_s[d][c * 12 + 4];
                const float  msc = Ms_s[d][c * 12 + 8];
                const float mcv[9] = {mca.x, mca.y, mca.z, mca.w, mcb.x, mcb.y, mcb.z, mcb.w, mcc};
                const float msv[9] = {msa.x, msa.y, msa.z, msa.w, msb.x, msb.y, msb.z, msb.w, msc};
#pragma unroll
                for (int l = 0; l < 9; l++) {
                    Tc0[l] += qa * mcv[l]; Tc1[l] += qb * mcv[l];
                    Ts0[l] += qa * msv[l]; Ts1[l] += qb * msv[l];
                }
            }
            const int tb0 = n0 * 200 + kk * 25 + u;
            const int tb1 = n1 * 200 + kk * 25 + u;
            const float cv0 = ckA[tb0], sv0 = skA[tb0];
            const float cv1 = ckA[tb1], sv1 = skA[tb1];
            float P0[9], P1[9];
#pragma unroll
            for (int l = 0; l < 9; l++) {
                P0[l] = cv0 * Tc0[l] + sv0 * Ts0[l];
                P1[l] = cv1 * Tc1[l] + sv1 * Ts1[l];
            }
#pragma unroll
            for (int l = 0; l < 9; l++) {
                const float4 ga = *(const float4*)&G_s[l * 12];
                const float4 gb = *(const float4*)&G_s[l * 12 + 4];
                const float  gc = G_s[l * 12 + 8];
                const float gv[9] = {ga.x, ga.y, ga.z, ga.w, gb.x, gb.y, gb.z, gb.w, gc};
#pragma unroll
                for (int m = 0; m < 9; m++) { om0[m] += P0[l] * gv[m]; om1[m] += P1[l] * gv[m]; }
            }
        }
    }
    const float zi0 = 1.0f / Z[n0 * 8 + h];
    const float zi1 = 1.0f / Z[n1 * 8 + h];
#pragma unroll
    for (int m = 0; m < 9; m++) {
        outm[((size_t)n0 * 9 + m) * 128 + h * 16 + c] = om0[m] * zi0;   // outm[n][m][h][c]
        outm[((size_t)n1 * 9 + m) * 128 + h * 16 + c] = om1[m] * zi1;
    }
}

// ================================ launcher =================================
extern "C" void kernel_launch(void* const* d_in, const int* in_sizes, int n_in,
                              void* d_out, int out_size, void* d_ws, size_t ws_size,
                              hipStream_t stream) {
    const float* pos  = (const float*)d_in[0];
    const float* feat = (const float*)d_in[1];
    const float* Wq   = (const float*)d_in[2];
    const float* Wk   = (const float*)d_in[3];
    const float* Wv   = (const float*)d_in[4];
    const float* Wo   = (const float*)d_in[5];
    const float* a    = (const float*)d_in[6];
    const float* kap  = (const float*)d_in[7];
    float* out = (float*)d_out;
    float* ws = (float*)d_ws;

    float* qf   = ws;                  // 524288
    float* kf   = qf + 524288;         // 524288
    float* v    = kf + 524288;         // 2359296
    float* ck   = v + 2359296;         // 409600
    float* sk   = ck + 409600;         // 409600
    float* R    = sk + 409600;         // 1572864
    float* ksum = R + 1572864;         // 256
    float* Z    = ksum + 256;          // 16384
    float* G    = Z + 16384;           // 129600
    float* Mv   = G + 129600;          // 14745600
    float* outm = Mv + 14745600;       // 2359296  (total ~92.2 MB)

    const float* cst = d_const_g;

    hipLaunchKernelGGL(radial_k, dim3(2048), dim3(256), 0, stream, feat, R);
    hipLaunchKernelGGL(gemm_k, dim3(4, 32), dim3(256), 0, stream, R, Wq, qf, 2048, 256, 768, 1);
    hipLaunchKernelGGL(gemm_k, dim3(4, 32), dim3(256), 0, stream, R, Wk, kf, 2048, 256, 768, 1);
    hipLaunchKernelGGL(gemm_k, dim3(2, 288), dim3(256), 0, stream, feat, Wv, v, 18432, 128, 256, 2);
    hipLaunchKernelGGL(trig_k, dim3(2048), dim3(256), 0, stream, pos, kap, cst, ck, sk);
    hipLaunchKernelGGL(ksum_k, dim3(1), dim3(256), 0, stream, kf, ksum);
    hipLaunchKernelGGL(z_k, dim3(64), dim3(256), 0, stream, qf, ksum, Z);
    hipLaunchKernelGGL(g_k, dim3(64), dim3(256), 0, stream, a, cst, G);
    hipLaunchKernelGGL(multipole_k, dim3(25, 8, 8), dim3(128), 0, stream, kf, v, ck, sk, Mv);
    hipLaunchKernelGGL(local_k, dim3(32, 8), dim3(512), 0, stream, qf, ck, sk, Mv, G, Z, outm);
    hipLaunchKernelGGL(gemm_k, dim3(4, 288), dim3(256), 0, stream, outm, Wo, out, 18432, 256, 128, 0);
}

// Round 2
// 2127.964 us; speedup vs baseline: 1.4524x; 1.4524x over previous
//
#include <hip/hip_runtime.h>
#include <cmath>
#include <complex>
#include <algorithm>

// ---------------------------------------------------------------------------
// Problem constants: LMAX=2, NC=9, H=8, DQK=32, CV=16, K=8, U=25, N=2048, C=256
// ---------------------------------------------------------------------------

typedef _Float16 half8 __attribute__((ext_vector_type(8)));
typedef _Float16 half4v __attribute__((ext_vector_type(4)));
typedef float float4v __attribute__((ext_vector_type(4)));

// ========================= host-side constant tables ========================
namespace {

using cd = std::complex<double>;

static double fct(int n) { double r = 1.0; for (int i = 2; i <= n; ++i) r *= i; return r; }

static double cg_coef(int j1, int m1, int j2, int m2, int j, int m) {
    if (m1 + m2 != m || j < std::abs(j1 - j2) || j > j1 + j2) return 0.0;
    double pref = std::sqrt((2 * j + 1) * fct(j + j1 - j2) * fct(j - j1 + j2) * fct(j1 + j2 - j) / fct(j1 + j2 + j + 1));
    pref *= std::sqrt(fct(j + m) * fct(j - m) * fct(j1 - m1) * fct(j1 + m1) * fct(j2 - m2) * fct(j2 + m2));
    double s = 0.0;
    for (int k = 0; k <= j1 + j2 - j; ++k) {
        int d0 = k, d1 = j1 + j2 - j - k, d2 = j1 - m1 - k, d3 = j2 + m2 - k, d4 = j - j2 + m1 + k, d5 = j - j1 - m2 + k;
        if (d0 < 0 || d1 < 0 || d2 < 0 || d3 < 0 || d4 < 0 || d5 < 0) continue;
        s += ((k & 1) ? -1.0 : 1.0) / (fct(d0) * fct(d1) * fct(d2) * fct(d3) * fct(d4) * fct(d5));
    }
    return pref * s;
}

static void umat(int l, cd u[5][5]) {
    for (int i = 0; i < 5; i++) for (int j = 0; j < 5; j++) u[i][j] = cd(0, 0);
    const double s = 1.0 / std::sqrt(2.0);
    for (int m = -l; m <= l; m++) {
        double sgn = (std::abs(m) & 1) ? -1.0 : 1.0;   // (-1)^m
        if (m > 0)      { u[l + m][l + m] = cd(sgn * s, 0); u[l + m][l - m] = cd(s, 0); }
        else if (m == 0){ u[l][l] = cd(1, 0); }
        else            { u[l + m][l + m] = cd(0, s);       u[l + m][l - m] = cd(0, -sgn * s); }
    }
}

static void real_cg_f(int l1, int l2, int L, double out[5][5][5]) {
    cd U1[5][5], U2[5][5], UL[5][5];
    umat(l1, U1); umat(l2, U2); umat(L, UL);
    const int n1 = 2 * l1 + 1, n2 = 2 * l2 + 1, n3 = 2 * L + 1;
    double cgt[5][5][5];
    for (int i1 = 0; i1 < n1; i1++) for (int i2 = 0; i2 < n2; i2++) for (int i3 = 0; i3 < n3; i3++)
        cgt[i1][i2][i3] = cg_coef(l1, i1 - l1, l2, i2 - l2, L, i3 - L);
    cd r[5][5][5];
    double nr = 0, ni = 0;
    for (int a1 = 0; a1 < n1; a1++) for (int b = 0; b < n2; b++) for (int c = 0; c < n3; c++) {
        cd acc(0, 0);
        for (int uu = 0; uu < n1; uu++) for (int vv = 0; vv < n2; vv++) for (int w = 0; w < n3; w++) {
            double cval = cgt[uu][vv][w];
            if (cval == 0.0) continue;
            acc += U1[a1][uu] * U2[b][vv] * std::conj(UL[c][w]) * cval;
        }
        r[a1][b][c] = acc;
        nr += acc.real() * acc.real();
        ni += acc.imag() * acc.imag();
    }
    const bool useRe = std::sqrt(nr) >= std::sqrt(ni);
    for (int a1 = 0; a1 < n1; a1++) for (int b = 0; b < n2; b++) for (int c = 0; c < n3; c++)
        out[a1][b][c] = useRe ? r[a1][b][c].real() : r[a1][b][c].imag();
}

// device constant buffer layout: YW[9*25] | RRED[9*81] | DIRS[25*3]  = 1029 floats
static float  h_const[1029];
static float* d_const_g = nullptr;

struct GlobalInit {
    GlobalInit() {
        const double PI = 3.14159265358979323846;
        const double gx[5] = {-0.9061798459386640, -0.5384693101056831, 0.0, 0.5384693101056831, 0.9061798459386640};
        const double gw[5] = { 0.23692688505618908, 0.47862867049936647, 0.5688888888888889, 0.47862867049936647, 0.23692688505618908};
        double YW[9][25], DIRS[25][3];
        for (int u = 0; u < 25; ++u) {
            const int it = u / 5, ip = u % 5;
            const double ct = gx[it], wq = gw[it] * (2.0 * PI / 5.0), ph = 2.0 * PI * ip / 5.0;
            const double st = std::sqrt(std::max(1.0 - ct * ct, 0.0));
            const double x = st * std::cos(ph), y = st * std::sin(ph), z = ct;
            DIRS[u][0] = x; DIRS[u][1] = y; DIRS[u][2] = z;
            double Y[9];
            Y[0] = 0.282095;           Y[1] = 0.488603 * y;      Y[2] = 0.488603 * z;
            Y[3] = 0.488603 * x;       Y[4] = 1.092548 * x * y;  Y[5] = 1.092548 * y * z;
            Y[6] = 0.315392 * (3 * z * z - 1); Y[7] = 1.092548 * x * z; Y[8] = 0.546274 * (x * x - y * y);
            for (int e = 0; e < 9; e++) YW[e][u] = Y[e] * wq;
        }
        double RRED[9][9][9];
        for (int i = 0; i < 9; i++) for (int j = 0; j < 9; j++) for (int k = 0; k < 9; k++) RRED[i][j][k] = 0.0;
        const int off[3] = {0, 1, 4};
        double cnt[3] = {0, 0, 0};
        double rc[5][5][5];
        for (int l1 = 0; l1 <= 2; l1++) for (int l2 = 0; l2 <= 2; l2++) {
            const int Llo = std::abs(l1 - l2), Lhi = std::min(l1 + l2, 2);
            for (int L = Llo; L <= Lhi; L++) {
                real_cg_f(l1, l2, L, rc);
                for (int i1 = 0; i1 < 2 * l1 + 1; i1++)
                    for (int i2 = 0; i2 < 2 * l2 + 1; i2++)
                        for (int i3 = 0; i3 < 2 * L + 1; i3++)
                            RRED[off[l1] + i1][off[l2] + i2][off[L] + i3] += rc[i1][i2][i3];
                cnt[L] += 1.0;
            }
        }
        for (int L = 0; L <= 2; L++) {
            const double dv = std::max(cnt[L], 1.0);
            for (int a1 = 0; a1 < 9; a1++) for (int b = 0; b < 9; b++)
                for (int k = 0; k < 2 * L + 1; k++) RRED[a1][b][off[L] + k] /= dv;
        }
        for (int e = 0; e < 9; e++) for (int u = 0; u < 25; u++) h_const[e * 25 + u] = (float)YW[e][u];
        for (int e = 0; e < 9; e++) for (int l = 0; l < 9; l++) for (int m = 0; m < 9; m++)
            h_const[225 + e * 81 + l * 9 + m] = (float)RRED[e][l][m];
        for (int u = 0; u < 25; u++) for (int ax = 0; ax < 3; ax++) h_const[954 + u * 3 + ax] = (float)DIRS[u][ax];
        if (hipMalloc((void**)&d_const_g, 1029 * sizeof(float)) == hipSuccess)
            hipMemcpy(d_const_g, h_const, 1029 * sizeof(float), hipMemcpyHostToDevice);
    }
} g_init;

} // namespace

// ============================== device kernels ==============================

// R[n][p][c]: p=0 -> feat(l=0); p=1 -> |l=1 block|; p=2 -> |l=2 block|
__global__ void radial_k(const float* __restrict__ feat, float* __restrict__ R) {
    const int n = blockIdx.x, c = threadIdx.x;
    const float* f = feat + (size_t)n * 9 * 256 + c;
    const float f0 = f[0];
    const float a1 = f[256], a2 = f[512], a3 = f[768];
    const float b1 = f[1024], b2 = f[1280], b3 = f[1536], b4 = f[1792], b5 = f[2048];
    const float r1 = sqrtf(a1 * a1 + a2 * a2 + a3 * a3 + 1e-8f);
    const float r2 = sqrtf(b1 * b1 + b2 * b2 + b3 * b3 + b4 * b4 + b5 * b5 + 1e-8f);
    float* o = R + (size_t)n * 768 + c;
    o[0] = f0; o[256] = r1; o[512] = r2;
}

// generic 64x64-tile f32 GEMM, C = A(MxK) @ B(KxN)
// mode 0 plain, 1 elu+1, 2 v-scatter, 3 plain with A-element scale by rZ[n][h]
__global__ __launch_bounds__(256) void gemm_k(const float* __restrict__ A, const float* __restrict__ B,
                                              float* __restrict__ Cv, int M, int N, int Kd, int mode,
                                              const float* __restrict__ rZ) {
    __shared__ float As[32][68];   // [k][row]
    __shared__ float Bs[32][68];   // [k][col]
    const int tid = threadIdx.x;
    const int tx = tid & 15, ty = tid >> 4;
    const int rb = blockIdx.y * 64, cb = blockIdx.x * 64;
    float acc[4][4];
#pragma unroll
    for (int i = 0; i < 4; i++) for (int j = 0; j < 4; j++) acc[i][j] = 0.f;
    for (int k0 = 0; k0 < Kd; k0 += 32) {
        __syncthreads();
#pragma unroll
        for (int i = 0; i < 2; i++) {
            const int idx = tid + i * 256;
            const int row = idx >> 3, kq = idx & 7;
            float4 av = *(const float4*)(A + (size_t)(rb + row) * Kd + k0 + kq * 4);
            if (mode == 3) {
                const int n = (rb + row) / 9;
                const int hh = (k0 + kq * 4) >> 4;
                const float rz = rZ[n * 8 + hh];
                av.x *= rz; av.y *= rz; av.z *= rz; av.w *= rz;
            }
            As[kq * 4 + 0][row] = av.x; As[kq * 4 + 1][row] = av.y;
            As[kq * 4 + 2][row] = av.z; As[kq * 4 + 3][row] = av.w;
        }
#pragma unroll
        for (int i = 0; i < 2; i++) {
            const int idx = tid + i * 256;
            const int kr = idx >> 4, cq = idx & 15;
            *(float4*)&Bs[kr][cq * 4] = *(const float4*)(B + (size_t)(k0 + kr) * N + cb + cq * 4);
        }
        __syncthreads();
#pragma unroll 8
        for (int k = 0; k < 32; k++) {
            const float4 a = *(const float4*)&As[k][ty * 4];
            const float4 b = *(const float4*)&Bs[k][tx * 4];
            const float av[4] = {a.x, a.y, a.z, a.w};
            const float bv[4] = {b.x, b.y, b.z, b.w};
#pragma unroll
            for (int i = 0; i < 4; i++)
#pragma unroll
                for (int j = 0; j < 4; j++) acc[i][j] += av[i] * bv[j];
        }
    }
#pragma unroll
    for (int i = 0; i < 4; i++) {
        const int r = rb + ty * 4 + i;
#pragma unroll
        for (int j = 0; j < 4; j++) {
            const int cc2 = cb + tx * 4 + j;
            float val = acc[i][j];
            if (mode == 1) val = (val > 0.f ? val : expf(val) - 1.f) + 1.f;
            if (mode == 2) {
                const int n = r / 9, l = r - n * 9, hq = cc2 >> 4, cvq = cc2 & 15;
                Cv[(((size_t)n * 8 + hq) * 16 + cvq) * 9 + l] = val;   // v[n][h][c][l]
            } else {
                Cv[(size_t)r * N + cc2] = val;
            }
        }
    }
}

// ck/sk[n][kk][u] = cos/sin(kappa_kk * pos_n . dir_u); also trigT[kkut][n] f32
__global__ void trig_k(const float* __restrict__ pos, const float* __restrict__ kappa,
                       const float* __restrict__ cst, float* __restrict__ ck, float* __restrict__ sk,
                       float* __restrict__ trigT) {
    const int n = blockIdx.x, t = threadIdx.x;
    if (t >= 200) return;
    const int kq = t / 25, u = t - kq * 25;
    const float* dirs = cst + 954;
    const float ph = kappa[kq] * (pos[n * 3] * dirs[u * 3] + pos[n * 3 + 1] * dirs[u * 3 + 1] + pos[n * 3 + 2] * dirs[u * 3 + 2]);
    float s, c;
    sincosf(ph, &s, &c);
    ck[(size_t)n * 200 + t] = c;
    sk[(size_t)n * 200 + t] = s;
    const int kkut = (kq * 25 + u) * 2;
    trigT[(size_t)kkut * 2048 + n] = c;
    trigT[(size_t)(kkut + 1) * 2048 + n] = s;
}

__global__ void ksum_k(const float* __restrict__ kf, float* __restrict__ ksum) {
    const int j = threadIdx.x;   // 256
    float s0 = 0, s1 = 0, s2 = 0, s3 = 0;
    for (int n = 0; n < 2048; n += 4) {
        s0 += kf[(size_t)n * 256 + j];
        s1 += kf[(size_t)(n + 1) * 256 + j];
        s2 += kf[(size_t)(n + 2) * 256 + j];
        s3 += kf[(size_t)(n + 3) * 256 + j];
    }
    ksum[j] = s0 + s1 + s2 + s3;
}

// rz[n][h] = 1 / (qf[n,h,:].ksum[h,:] + 1e-6)
__global__ void z_k(const float* __restrict__ qf, const float* __restrict__ ksum, float* __restrict__ rz) {
    const int idx = blockIdx.x * 256 + threadIdx.x;   // N*H = 16384
    const int n = idx >> 3, h = idx & 7;
    float s = 0.f;
#pragma unroll
    for (int d = 0; d < 32; d++) s += qf[(size_t)n * 256 + h * 32 + d] * ksum[h * 32 + d];
    rz[idx] = 1.0f / (s + 1e-6f);
}

// G[kk][h][u][l*9+m] = sum_e aE[e,h,kk] * YW[e,u] * RRED[e,l,m]
__global__ void g_k(const float* __restrict__ a, const float* __restrict__ cst, float* __restrict__ G) {
    const int kk = blockIdx.x & 7, h = blockIdx.x >> 3;
    __shared__ float ae[9];
    if (threadIdx.x < 9) {
        const int ldeg[9] = {0, 1, 1, 1, 2, 2, 2, 2, 2};
        ae[threadIdx.x] = a[ldeg[threadIdx.x] * 64 + h * 8 + kk];
    }
    __syncthreads();
    const float* yw = cst;
    const float* rred = cst + 225;
    for (int i = threadIdx.x; i < 25 * 81; i += 256) {
        const int u = i / 81, lm = i - u * 81;
        float s = 0.f;
#pragma unroll
        for (int e = 0; e < 9; e++) s += ae[e] * yw[e * 25 + u] * rred[e * 81 + lm];
        G[((size_t)(kk * 8 + h) * 25 + u) * 81 + lm] = s;
    }
}

// M[kkut][h][d][c*9+l] (f16) = sum_n trig[n,kk,u,t] * kf[n,h,d] * v[n,h,c,l]
//   kkut = (kk*25+u)*2 + t,  t=0 cos / t=1 sin
__global__ __launch_bounds__(128) void multipole_k(const float* __restrict__ kf, const float* __restrict__ v,
                                                   const float* __restrict__ ckA, const float* __restrict__ skA,
                                                   _Float16* __restrict__ Mv) {
    const int u = blockIdx.x, kk = blockIdx.y, h = blockIdx.z;
    const int tid = threadIdx.x;
    const int d = tid & 31, g = tid >> 5;   // g: 0..3, 36 cl each
    __shared__ float kf_s[16][32];
    __shared__ float v_s[16][144];
    __shared__ float c_s[16], s_s[16];
    float accC[36], accS[36];
#pragma unroll
    for (int i = 0; i < 36; i++) { accC[i] = 0.f; accS[i] = 0.f; }
    const int tb = kk * 25 + u;
    for (int nb = 0; nb < 2048; nb += 16) {
        __syncthreads();
        {
            const int n = tid >> 3, q = tid & 7;
            *(float4*)&kf_s[n][q * 4] = *(const float4*)(kf + (size_t)(nb + n) * 256 + h * 32 + q * 4);
        }
        for (int j = tid; j < 576; j += 128) {
            const int n = j / 36, q = j - n * 36;
            *(float4*)&v_s[n][q * 4] = *(const float4*)(v + ((size_t)(nb + n) * 8 + h) * 144 + q * 4);
        }
        if (tid < 16)       c_s[tid] = ckA[(size_t)(nb + tid) * 200 + tb];
        else if (tid < 32)  s_s[tid - 16] = skA[(size_t)(nb + tid - 16) * 200 + tb];
        __syncthreads();
#pragma unroll 4
        for (int n = 0; n < 16; n++) {
            const float kd = kf_s[n][d];
            const float ac = c_s[n] * kd, as_ = s_s[n] * kd;
#pragma unroll
            for (int i = 0; i < 9; i++) {
                const float4 vv = *(const float4*)&v_s[n][g * 36 + i * 4];
                accC[i * 4 + 0] += ac * vv.x; accC[i * 4 + 1] += ac * vv.y;
                accC[i * 4 + 2] += ac * vv.z; accC[i * 4 + 3] += ac * vv.w;
                accS[i * 4 + 0] += as_ * vv.x; accS[i * 4 + 1] += as_ * vv.y;
                accS[i * 4 + 2] += as_ * vv.z; accS[i * 4 + 3] += as_ * vv.w;
            }
        }
    }
    {
        _Float16* dst = Mv + (((size_t)tb * 2 + 0) * 8 + h) * 4608 + d * 144 + g * 36;
#pragma unroll
        for (int i = 0; i < 9; i++)
            *(half4v*)(dst + i * 4) = half4v{(_Float16)accC[i * 4], (_Float16)accC[i * 4 + 1],
                                             (_Float16)accC[i * 4 + 2], (_Float16)accC[i * 4 + 3]};
    }
    {
        _Float16* dst = Mv + (((size_t)tb * 2 + 1) * 8 + h) * 4608 + d * 144 + g * 36;
#pragma unroll
        for (int i = 0; i < 9; i++)
            *(half4v*)(dst + i * 4) = half4v{(_Float16)accS[i * 4], (_Float16)accS[i * 4 + 1],
                                             (_Float16)accS[i * 4 + 2], (_Float16)accS[i * 4 + 3]};
    }
}

// MG[kkut][h][quad][cm][8] (f16) = sum_l M[kkut][h][d][c*9+l] * G[kk,h,u][l*9+m]
//   cm = c*9+m, d = quad*8+j  (B-fragment friendly layout for mfma 16x16x32)
__global__ __launch_bounds__(256) void fold_k(const _Float16* __restrict__ Mv, const float* __restrict__ G,
                                              _Float16* __restrict__ MG) {
    const int kt = blockIdx.x, h = blockIdx.y;
    const int tid = threadIdx.x;
    __shared__ float ms[4608];
    __shared__ float gs[81];
    const _Float16* src = Mv + ((size_t)kt * 8 + h) * 4608;
    for (int i = tid; i < 4608; i += 256) ms[i] = (float)src[i];
    const int kk = kt / 50, u = (kt >> 1) % 25;
    if (tid < 81) gs[tid] = G[(((size_t)kk * 8 + h) * 25 + u) * 81 + tid];
    __syncthreads();
    _Float16* dst = MG + ((size_t)kt * 8 + h) * 4608;
    for (int i = tid; i < 4608; i += 256) {
        const int quad = i / 1152, r = i - quad * 1152;
        const int cm = r >> 3, j = r & 7;
        const int d = quad * 8 + j, c = cm / 9, m = cm - c * 9;
        float s = 0.f;
#pragma unroll
        for (int l = 0; l < 9; l++) s += ms[d * 144 + c * 9 + l] * gs[l * 9 + m];
        dst[i] = (_Float16)s;
    }
}

// local stage via MFMA: outm[n][m][h][c] += sum_{kkut,d} trig[kkut][n]*qf[n,h,d] * MG[kkut][h][cm][d]
// grid (16 ngroups, 8 h, 4 kk-slices); block 256 = 4 waves; wave: 32 n x 144 cm
__global__ __launch_bounds__(256) void mm_local_k(const float* __restrict__ qf, const float* __restrict__ trigT,
                                                  const _Float16* __restrict__ MG, float* __restrict__ outm) {
    const int h = blockIdx.y;
    const int n0 = blockIdx.x * 128;
    const int slice = blockIdx.z;
    const int tid = threadIdx.x;
    const int w = tid >> 6, lane = tid & 63;
    const int l15 = lane & 15, quad = lane >> 4;

    __shared__ __align__(16) _Float16 mg_s[4608];

    const int nbase = n0 + w * 32;
    float qfr[2][8];
#pragma unroll
    for (int rt = 0; rt < 2; rt++) {
        const int n = nbase + rt * 16 + l15;
        const float* qp = qf + (size_t)n * 256 + h * 32 + quad * 8;
#pragma unroll
        for (int j = 0; j < 8; j++) qfr[rt][j] = qp[j];
    }
    float4v acc[2][9];
#pragma unroll
    for (int rt = 0; rt < 2; rt++)
#pragma unroll
        for (int ct = 0; ct < 9; ct++) acc[rt][ct] = float4v{0.f, 0.f, 0.f, 0.f};

    const int kt0 = slice * 100;
    for (int kt = kt0; kt < kt0 + 100; kt++) {
        __syncthreads();
        // stage MG slab (9216 B) into LDS
        {
            const uint4* src = (const uint4*)(MG + ((size_t)kt * 8 + h) * 4608);
            uint4* dstl = (uint4*)mg_s;
            for (int i = tid; i < 576; i += 256) dstl[i] = src[i];
        }
        __syncthreads();
        // A fragments: trig[kkut][n] * qf[n][d],  d = quad*8+j
        half8 af[2];
#pragma unroll
        for (int rt = 0; rt < 2; rt++) {
            const float tv = trigT[(size_t)kt * 2048 + nbase + rt * 16 + l15];
#pragma unroll
            for (int j = 0; j < 8; j++) af[rt][j] = (_Float16)(tv * qfr[rt][j]);
        }
#pragma unroll
        for (int ct = 0; ct < 9; ct++) {
            const half8 b = *(const half8*)&mg_s[quad * 1152 + (ct * 16 + l15) * 8];
            acc[0][ct] = __builtin_amdgcn_mfma_f32_16x16x32_f16(af[0], b, acc[0][ct], 0, 0, 0);
            acc[1][ct] = __builtin_amdgcn_mfma_f32_16x16x32_f16(af[1], b, acc[1][ct], 0, 0, 0);
        }
    }
    // epilogue: atomic-add partials into outm[n][m][h][c]
#pragma unroll
    for (int rt = 0; rt < 2; rt++)
#pragma unroll
        for (int ct = 0; ct < 9; ct++) {
#pragma unroll
            for (int r = 0; r < 4; r++) {
                const int n = nbase + rt * 16 + quad * 4 + r;
                const int cm = ct * 16 + l15;
                const int c = cm / 9, m = cm - c * 9;
                atomicAdd(&outm[((size_t)n * 9 + m) * 128 + h * 16 + c], acc[rt][ct][r]);
            }
        }
}

// ================================ launcher =================================
extern "C" void kernel_launch(void* const* d_in, const int* in_sizes, int n_in,
                              void* d_out, int out_size, void* d_ws, size_t ws_size,
                              hipStream_t stream) {
    const float* pos  = (const float*)d_in[0];
    const float* feat = (const float*)d_in[1];
    const float* Wq   = (const float*)d_in[2];
    const float* Wk   = (const float*)d_in[3];
    const float* Wv   = (const float*)d_in[4];
    const float* Wo   = (const float*)d_in[5];
    const float* a    = (const float*)d_in[6];
    const float* kap  = (const float*)d_in[7];
    float* out = (float*)d_out;
    float* ws = (float*)d_ws;

    // float-slot layout (total ~22.3M slots = 89.2 MB)
    float* qf    = ws;                    // 524288
    float* kf    = qf + 524288;           // 524288
    float* v     = kf + 524288;           // 2359296
    float* ck    = v + 2359296;           // 409600
    float* sk    = ck + 409600;           // 409600
    float* trigT = sk + 409600;           // 819200
    float* ksum  = trigT + 819200;        // 256
    float* rz    = ksum + 256;            // 16384
    float* G     = rz + 16384;            // 129600
    float* MvF   = G + 129600;            // 7372800 slots (f16 x 14745600)
    float* outm  = MvF + 7372800;         // 2359296
    float* regX  = outm + 2359296;        // 7372800 slots: R (first 1572864) then reused as MG f16
    float* R     = regX;
    _Float16* Mv16 = (_Float16*)MvF;
    _Float16* MG16 = (_Float16*)regX;

    const float* cst = d_const_g;

    hipLaunchKernelGGL(radial_k, dim3(2048), dim3(256), 0, stream, feat, R);
    hipLaunchKernelGGL(gemm_k, dim3(4, 32), dim3(256), 0, stream, R, Wq, qf, 2048, 256, 768, 1, rz);
    hipLaunchKernelGGL(gemm_k, dim3(4, 32), dim3(256), 0, stream, R, Wk, kf, 2048, 256, 768, 1, rz);
    hipLaunchKernelGGL(gemm_k, dim3(2, 288), dim3(256), 0, stream, feat, Wv, v, 18432, 128, 256, 2, rz);
    hipLaunchKernelGGL(trig_k, dim3(2048), dim3(256), 0, stream, pos, kap, cst, ck, sk, trigT);
    hipLaunchKernelGGL(ksum_k, dim3(1), dim3(256), 0, stream, kf, ksum);
    hipLaunchKernelGGL(z_k, dim3(64), dim3(256), 0, stream, qf, ksum, rz);
    hipLaunchKernelGGL(g_k, dim3(64), dim3(256), 0, stream, a, cst, G);
    hipLaunchKernelGGL(multipole_k, dim3(25, 8, 8), dim3(128), 0, stream, kf, v, ck, sk, Mv16);
    hipLaunchKernelGGL(fold_k, dim3(400, 8), dim3(256), 0, stream, Mv16, G, MG16);
    hipMemsetAsync(outm, 0, 2359296 * sizeof(float), stream);
    hipLaunchKernelGGL(mm_local_k, dim3(16, 8, 4), dim3(256), 0, stream, qf, trigT, MG16, outm);
    hipLaunchKernelGGL(gemm_k, dim3(4, 288), dim3(256), 0, stream, outm, Wo, out, 18432, 256, 128, 3, rz);
}

// Round 3
// 917.057 us; speedup vs baseline: 3.3703x; 2.3204x over previous
//
#include <hip/hip_runtime.h>
#include <cmath>
#include <complex>
#include <algorithm>

// ---------------------------------------------------------------------------
// Problem constants: LMAX=2, NC=9, H=8, DQK=32, CV=16, K=8, U=25, N=2048, C=256
// ---------------------------------------------------------------------------

typedef _Float16 half8 __attribute__((ext_vector_type(8)));
typedef _Float16 half4v __attribute__((ext_vector_type(4)));
typedef float float4v __attribute__((ext_vector_type(4)));

// ========================= host-side constant tables ========================
namespace {

using cd = std::complex<double>;

static double fct(int n) { double r = 1.0; for (int i = 2; i <= n; ++i) r *= i; return r; }

static double cg_coef(int j1, int m1, int j2, int m2, int j, int m) {
    if (m1 + m2 != m || j < std::abs(j1 - j2) || j > j1 + j2) return 0.0;
    double pref = std::sqrt((2 * j + 1) * fct(j + j1 - j2) * fct(j - j1 + j2) * fct(j1 + j2 - j) / fct(j1 + j2 + j + 1));
    pref *= std::sqrt(fct(j + m) * fct(j - m) * fct(j1 - m1) * fct(j1 + m1) * fct(j2 - m2) * fct(j2 + m2));
    double s = 0.0;
    for (int k = 0; k <= j1 + j2 - j; ++k) {
        int d0 = k, d1 = j1 + j2 - j - k, d2 = j1 - m1 - k, d3 = j2 + m2 - k, d4 = j - j2 + m1 + k, d5 = j - j1 - m2 + k;
        if (d0 < 0 || d1 < 0 || d2 < 0 || d3 < 0 || d4 < 0 || d5 < 0) continue;
        s += ((k & 1) ? -1.0 : 1.0) / (fct(d0) * fct(d1) * fct(d2) * fct(d3) * fct(d4) * fct(d5));
    }
    return pref * s;
}

static void umat(int l, cd u[5][5]) {
    for (int i = 0; i < 5; i++) for (int j = 0; j < 5; j++) u[i][j] = cd(0, 0);
    const double s = 1.0 / std::sqrt(2.0);
    for (int m = -l; m <= l; m++) {
        double sgn = (std::abs(m) & 1) ? -1.0 : 1.0;   // (-1)^m
        if (m > 0)      { u[l + m][l + m] = cd(sgn * s, 0); u[l + m][l - m] = cd(s, 0); }
        else if (m == 0){ u[l][l] = cd(1, 0); }
        else            { u[l + m][l + m] = cd(0, s);       u[l + m][l - m] = cd(0, -sgn * s); }
    }
}

static void real_cg_f(int l1, int l2, int L, double out[5][5][5]) {
    cd U1[5][5], U2[5][5], UL[5][5];
    umat(l1, U1); umat(l2, U2); umat(L, UL);
    const int n1 = 2 * l1 + 1, n2 = 2 * l2 + 1, n3 = 2 * L + 1;
    double cgt[5][5][5];
    for (int i1 = 0; i1 < n1; i1++) for (int i2 = 0; i2 < n2; i2++) for (int i3 = 0; i3 < n3; i3++)
        cgt[i1][i2][i3] = cg_coef(l1, i1 - l1, l2, i2 - l2, L, i3 - L);
    cd r[5][5][5];
    double nr = 0, ni = 0;
    for (int a1 = 0; a1 < n1; a1++) for (int b = 0; b < n2; b++) for (int c = 0; c < n3; c++) {
        cd acc(0, 0);
        for (int uu = 0; uu < n1; uu++) for (int vv = 0; vv < n2; vv++) for (int w = 0; w < n3; w++) {
            double cval = cgt[uu][vv][w];
            if (cval == 0.0) continue;
            acc += U1[a1][uu] * U2[b][vv] * std::conj(UL[c][w]) * cval;
        }
        r[a1][b][c] = acc;
        nr += acc.real() * acc.real();
        ni += acc.imag() * acc.imag();
    }
    const bool useRe = std::sqrt(nr) >= std::sqrt(ni);
    for (int a1 = 0; a1 < n1; a1++) for (int b = 0; b < n2; b++) for (int c = 0; c < n3; c++)
        out[a1][b][c] = useRe ? r[a1][b][c].real() : r[a1][b][c].imag();
}

// device constant buffer layout: YW[9*25] | RRED[9*81] | DIRS[25*3]  = 1029 floats
static float  h_const[1029];
static float* d_const_g = nullptr;

struct GlobalInit {
    GlobalInit() {
        const double PI = 3.14159265358979323846;
        const double gx[5] = {-0.9061798459386640, -0.5384693101056831, 0.0, 0.5384693101056831, 0.9061798459386640};
        const double gw[5] = { 0.23692688505618908, 0.47862867049936647, 0.5688888888888889, 0.47862867049936647, 0.23692688505618908};
        double YW[9][25], DIRS[25][3];
        for (int u = 0; u < 25; ++u) {
            const int it = u / 5, ip = u % 5;
            const double ct = gx[it], wq = gw[it] * (2.0 * PI / 5.0), ph = 2.0 * PI * ip / 5.0;
            const double st = std::sqrt(std::max(1.0 - ct * ct, 0.0));
            const double x = st * std::cos(ph), y = st * std::sin(ph), z = ct;
            DIRS[u][0] = x; DIRS[u][1] = y; DIRS[u][2] = z;
            double Y[9];
            Y[0] = 0.282095;           Y[1] = 0.488603 * y;      Y[2] = 0.488603 * z;
            Y[3] = 0.488603 * x;       Y[4] = 1.092548 * x * y;  Y[5] = 1.092548 * y * z;
            Y[6] = 0.315392 * (3 * z * z - 1); Y[7] = 1.092548 * x * z; Y[8] = 0.546274 * (x * x - y * y);
            for (int e = 0; e < 9; e++) YW[e][u] = Y[e] * wq;
        }
        double RRED[9][9][9];
        for (int i = 0; i < 9; i++) for (int j = 0; j < 9; j++) for (int k = 0; k < 9; k++) RRED[i][j][k] = 0.0;
        const int off[3] = {0, 1, 4};
        double cnt[3] = {0, 0, 0};
        double rc[5][5][5];
        for (int l1 = 0; l1 <= 2; l1++) for (int l2 = 0; l2 <= 2; l2++) {
            const int Llo = std::abs(l1 - l2), Lhi = std::min(l1 + l2, 2);
            for (int L = Llo; L <= Lhi; L++) {
                real_cg_f(l1, l2, L, rc);
                for (int i1 = 0; i1 < 2 * l1 + 1; i1++)
                    for (int i2 = 0; i2 < 2 * l2 + 1; i2++)
                        for (int i3 = 0; i3 < 2 * L + 1; i3++)
                            RRED[off[l1] + i1][off[l2] + i2][off[L] + i3] += rc[i1][i2][i3];
                cnt[L] += 1.0;
            }
        }
        for (int L = 0; L <= 2; L++) {
            const double dv = std::max(cnt[L], 1.0);
            for (int a1 = 0; a1 < 9; a1++) for (int b = 0; b < 9; b++)
                for (int k = 0; k < 2 * L + 1; k++) RRED[a1][b][off[L] + k] /= dv;
        }
        for (int e = 0; e < 9; e++) for (int u = 0; u < 25; u++) h_const[e * 25 + u] = (float)YW[e][u];
        for (int e = 0; e < 9; e++) for (int l = 0; l < 9; l++) for (int m = 0; m < 9; m++)
            h_const[225 + e * 81 + l * 9 + m] = (float)RRED[e][l][m];
        for (int u = 0; u < 25; u++) for (int ax = 0; ax < 3; ax++) h_const[954 + u * 3 + ax] = (float)DIRS[u][ax];
        if (hipMalloc((void**)&d_const_g, 1029 * sizeof(float)) == hipSuccess)
            hipMemcpy(d_const_g, h_const, 1029 * sizeof(float), hipMemcpyHostToDevice);
    }
} g_init;

} // namespace

// ============================== device kernels ==============================

// R[n][p][c]: p=0 -> feat(l=0); p=1 -> |l=1 block|; p=2 -> |l=2 block|
__global__ void radial_k(const float* __restrict__ feat, float* __restrict__ R) {
    const int n = blockIdx.x, c = threadIdx.x;
    const float* f = feat + (size_t)n * 9 * 256 + c;
    const float f0 = f[0];
    const float a1 = f[256], a2 = f[512], a3 = f[768];
    const float b1 = f[1024], b2 = f[1280], b3 = f[1536], b4 = f[1792], b5 = f[2048];
    const float r1 = sqrtf(a1 * a1 + a2 * a2 + a3 * a3 + 1e-8f);
    const float r2 = sqrtf(b1 * b1 + b2 * b2 + b3 * b3 + b4 * b4 + b5 * b5 + 1e-8f);
    float* o = R + (size_t)n * 768 + c;
    o[0] = f0; o[256] = r1; o[512] = r2;
}

// generic 64x64-tile f32 GEMM, C = A(MxK) @ B(KxN)
// mode 0 plain, 1 elu+1, 2 v-scatter, 3 plain with A-element scale by rZ[n][h]
__global__ __launch_bounds__(256) void gemm_k(const float* __restrict__ A, const float* __restrict__ B,
                                              float* __restrict__ Cv, int M, int N, int Kd, int mode,
                                              const float* __restrict__ rZ) {
    __shared__ float As[32][68];   // [k][row]
    __shared__ float Bs[32][68];   // [k][col]
    const int tid = threadIdx.x;
    const int tx = tid & 15, ty = tid >> 4;
    const int rb = blockIdx.y * 64, cb = blockIdx.x * 64;
    float acc[4][4];
#pragma unroll
    for (int i = 0; i < 4; i++) for (int j = 0; j < 4; j++) acc[i][j] = 0.f;
    for (int k0 = 0; k0 < Kd; k0 += 32) {
        __syncthreads();
#pragma unroll
        for (int i = 0; i < 2; i++) {
            const int idx = tid + i * 256;
            const int row = idx >> 3, kq = idx & 7;
            float4 av = *(const float4*)(A + (size_t)(rb + row) * Kd + k0 + kq * 4);
            if (mode == 3) {
                const int n = (rb + row) / 9;
                const int hh = (k0 + kq * 4) >> 4;
                const float rz = rZ[n * 8 + hh];
                av.x *= rz; av.y *= rz; av.z *= rz; av.w *= rz;
            }
            As[kq * 4 + 0][row] = av.x; As[kq * 4 + 1][row] = av.y;
            As[kq * 4 + 2][row] = av.z; As[kq * 4 + 3][row] = av.w;
        }
#pragma unroll
        for (int i = 0; i < 2; i++) {
            const int idx = tid + i * 256;
            const int kr = idx >> 4, cq = idx & 15;
            *(float4*)&Bs[kr][cq * 4] = *(const float4*)(B + (size_t)(k0 + kr) * N + cb + cq * 4);
        }
        __syncthreads();
#pragma unroll 8
        for (int k = 0; k < 32; k++) {
            const float4 a = *(const float4*)&As[k][ty * 4];
            const float4 b = *(const float4*)&Bs[k][tx * 4];
            const float av[4] = {a.x, a.y, a.z, a.w};
            const float bv[4] = {b.x, b.y, b.z, b.w};
#pragma unroll
            for (int i = 0; i < 4; i++)
#pragma unroll
                for (int j = 0; j < 4; j++) acc[i][j] += av[i] * bv[j];
        }
    }
#pragma unroll
    for (int i = 0; i < 4; i++) {
        const int r = rb + ty * 4 + i;
#pragma unroll
        for (int j = 0; j < 4; j++) {
            const int cc2 = cb + tx * 4 + j;
            float val = acc[i][j];
            if (mode == 1) val = (val > 0.f ? val : expf(val) - 1.f) + 1.f;
            if (mode == 2) {
                const int n = r / 9, l = r - n * 9, hq = cc2 >> 4, cvq = cc2 & 15;
                Cv[(((size_t)n * 8 + hq) * 16 + cvq) * 9 + l] = val;   // v[n][h][c][l]
            } else {
                Cv[(size_t)r * N + cc2] = val;
            }
        }
    }
}

// trig16[kkut][n] (f16) = cos/sin(kappa_kk * pos_n . dir_u); kkut = (kk*25+u)*2 + t
__global__ void trig_k(const float* __restrict__ pos, const float* __restrict__ kappa,
                       const float* __restrict__ cst, _Float16* __restrict__ trig16) {
    const int n = blockIdx.x, t = threadIdx.x;
    if (t >= 200) return;
    const int kq = t / 25, u = t - kq * 25;
    const float* dirs = cst + 954;
    const float ph = kappa[kq] * (pos[n * 3] * dirs[u * 3] + pos[n * 3 + 1] * dirs[u * 3 + 1] + pos[n * 3 + 2] * dirs[u * 3 + 2]);
    float s, c;
    sincosf(ph, &s, &c);
    const int kkut = (kq * 25 + u) * 2;
    trig16[(size_t)kkut * 2048 + n] = (_Float16)c;
    trig16[(size_t)(kkut + 1) * 2048 + n] = (_Float16)s;
}

__global__ void ksum_k(const float* __restrict__ kf, float* __restrict__ ksum) {
    const int j = threadIdx.x;   // 256
    float s0 = 0, s1 = 0, s2 = 0, s3 = 0;
    for (int n = 0; n < 2048; n += 4) {
        s0 += kf[(size_t)n * 256 + j];
        s1 += kf[(size_t)(n + 1) * 256 + j];
        s2 += kf[(size_t)(n + 2) * 256 + j];
        s3 += kf[(size_t)(n + 3) * 256 + j];
    }
    ksum[j] = s0 + s1 + s2 + s3;
}

// rz[n][h] = 1 / (qf[n,h,:].ksum[h,:] + 1e-6)
__global__ void z_k(const float* __restrict__ qf, const float* __restrict__ ksum, float* __restrict__ rz) {
    const int idx = blockIdx.x * 256 + threadIdx.x;   // N*H = 16384
    const int n = idx >> 3, h = idx & 7;
    float s = 0.f;
#pragma unroll
    for (int d = 0; d < 32; d++) s += qf[(size_t)n * 256 + h * 32 + d] * ksum[h * 32 + d];
    rz[idx] = 1.0f / (s + 1e-6f);
}

// G[kk][h][u][l*9+m] = sum_e aE[e,h,kk] * YW[e,u] * RRED[e,l,m]
__global__ void g_k(const float* __restrict__ a, const float* __restrict__ cst, float* __restrict__ G) {
    const int kk = blockIdx.x & 7, h = blockIdx.x >> 3;
    __shared__ float ae[9];
    if (threadIdx.x < 9) {
        const int ldeg[9] = {0, 1, 1, 1, 2, 2, 2, 2, 2};
        ae[threadIdx.x] = a[ldeg[threadIdx.x] * 64 + h * 8 + kk];
    }
    __syncthreads();
    const float* yw = cst;
    const float* rred = cst + 225;
    for (int i = threadIdx.x; i < 25 * 81; i += 256) {
        const int u = i / 81, lm = i - u * 81;
        float s = 0.f;
#pragma unroll
        for (int e = 0; e < 9; e++) s += ae[e] * yw[e * 25 + u] * rred[e * 81 + lm];
        G[((size_t)(kk * 8 + h) * 25 + u) * 81 + lm] = s;
    }
}

// MFMA multipole: per h, M16[kkut][h][j] = sum_n trig16[kkut][n] * W[n][j],
//   j = cl*32 + d,  W[n][cl*32+d] = kf[n,h,d] * v[n,h,cl]
// tile: 128 rows (kkut, padded to 512) x 64 cols (2 cl x 32 d); 4 row-split waves
__global__ __launch_bounds__(256) void multipole_mm_k(const _Float16* __restrict__ trig16,
                                                      const float* __restrict__ kf,
                                                      const float* __restrict__ v,
                                                      _Float16* __restrict__ M16) {
    const int cl0 = blockIdx.x * 2;          // 2 cl values per block
    const int cb  = blockIdx.x * 64;         // global col base
    const int rb  = blockIdx.y * 128;        // kkut row base (rows padded to 512)
    const int h   = blockIdx.z;
    const int tid = threadIdx.x;
    const int w = tid >> 6, lane = tid & 63;
    const int l15 = lane & 15, quad = lane >> 4;

    __shared__ __align__(16) _Float16 Ws[64 * 40];   // [col][n], row stride 40 f16 (80 B)

    float4v acc[2][4];
#pragma unroll
    for (int rt = 0; rt < 2; rt++)
#pragma unroll
        for (int s = 0; s < 4; s++) acc[rt][s] = float4v{0.f, 0.f, 0.f, 0.f};

    const int r0 = rb + w * 32;
    const int sn = tid >> 3, sq = tid & 7;   // stager: n-row, d-quartet

    for (int nb = 0; nb < 2048; nb += 32) {
        // ---- stage + build W tile (from registers, no kf round-trip) ----
        const float4 kv = *(const float4*)(kf + (size_t)(nb + sn) * 256 + h * 32 + sq * 4);
        const float v0 = v[((size_t)(nb + sn) * 8 + h) * 144 + cl0];
        const float v1 = v[((size_t)(nb + sn) * 8 + h) * 144 + cl0 + 1];
        __syncthreads();   // protect Ws against previous iteration's readers
        {
            const int d0 = sq * 4;
            // cl slot 0: cols d0..d0+3 ; cl slot 1: cols 32+d0..32+d0+3
            Ws[(d0 + 0) * 40 + sn] = (_Float16)(kv.x * v0);
            Ws[(d0 + 1) * 40 + sn] = (_Float16)(kv.y * v0);
            Ws[(d0 + 2) * 40 + sn] = (_Float16)(kv.z * v0);
            Ws[(d0 + 3) * 40 + sn] = (_Float16)(kv.w * v0);
            Ws[(32 + d0 + 0) * 40 + sn] = (_Float16)(kv.x * v1);
            Ws[(32 + d0 + 1) * 40 + sn] = (_Float16)(kv.y * v1);
            Ws[(32 + d0 + 2) * 40 + sn] = (_Float16)(kv.z * v1);
            Ws[(32 + d0 + 3) * 40 + sn] = (_Float16)(kv.w * v1);
        }
        __syncthreads();
        // ---- A fragments (direct f16 global, L2-resident trig16) ----
        half8 af[2];
#pragma unroll
        for (int rt = 0; rt < 2; rt++)
            af[rt] = *(const half8*)(trig16 + (size_t)(r0 + rt * 16 + l15) * 2048 + nb + quad * 8);
        // ---- MFMA over 4 col-subtiles ----
#pragma unroll
        for (int s = 0; s < 4; s++) {
            const half8 b = *(const half8*)&Ws[(s * 16 + l15) * 40 + quad * 8];
            acc[0][s] = __builtin_amdgcn_mfma_f32_16x16x32_f16(af[0], b, acc[0][s], 0, 0, 0);
            acc[1][s] = __builtin_amdgcn_mfma_f32_16x16x32_f16(af[1], b, acc[1][s], 0, 0, 0);
        }
    }
    // epilogue: C fragment (col=lane&15, row=quad*4+reg) -> M16[kkut][h][col]
#pragma unroll
    for (int rt = 0; rt < 2; rt++)
#pragma unroll
        for (int s = 0; s < 4; s++)
#pragma unroll
            for (int r = 0; r < 4; r++) {
                const int row = r0 + rt * 16 + quad * 4 + r;
                const int col = cb + s * 16 + l15;
                M16[((size_t)row * 8 + h) * 4608 + col] = (_Float16)acc[rt][s][r];
            }
}

// MG[kkut][h][quad][cm][8j] (f16) = sum_l M16[kkut][h][(c*9+l)*32+d] * G[kk,h,u][l*9+m]
//   cm = c*9+m, d = quad*8+j
__global__ __launch_bounds__(256) void fold_k(const _Float16* __restrict__ Mv, const float* __restrict__ G,
                                              _Float16* __restrict__ MG) {
    const int kt = blockIdx.x, h = blockIdx.y;
    const int tid = threadIdx.x;
    __shared__ float ms[144 * 33];   // [cl][d] padded 33
    __shared__ float gs[81];
    const _Float16* src = Mv + ((size_t)kt * 8 + h) * 4608;
    for (int i = tid; i < 4608; i += 256) {
        const int cl = i >> 5, d = i & 31;
        ms[cl * 33 + d] = (float)src[i];
    }
    const int kk = kt / 50, u = (kt >> 1) % 25;
    if (tid < 81) gs[tid] = G[(((size_t)kk * 8 + h) * 25 + u) * 81 + tid];
    __syncthreads();
    _Float16* dst = MG + ((size_t)kt * 8 + h) * 4608;
    for (int i = tid; i < 4608; i += 256) {
        const int quad = i / 1152, r = i - quad * 1152;
        const int cm = r >> 3, j = r & 7;
        const int d = quad * 8 + j, c = cm / 9, m = cm - c * 9;
        float s = 0.f;
#pragma unroll
        for (int l = 0; l < 9; l++) s += ms[(c * 9 + l) * 33 + d] * gs[l * 9 + m];
        dst[i] = (_Float16)s;
    }
}

// local stage via MFMA: outm[n][m][h][c] += sum_{kkut,d} trig[kkut][n]*qf[n,h,d] * MG[kkut][h][cm][d]
// grid (16 ngroups, 8 h, 4 kk-slices); block 256 = 4 waves; wave: 32 n x 144 cm
__global__ __launch_bounds__(256) void mm_local_k(const float* __restrict__ qf, const _Float16* __restrict__ trig16,
                                                  const _Float16* __restrict__ MG, float* __restrict__ outm) {
    const int h = blockIdx.y;
    const int n0 = blockIdx.x * 128;
    const int slice = blockIdx.z;
    const int tid = threadIdx.x;
    const int w = tid >> 6, lane = tid & 63;
    const int l15 = lane & 15, quad = lane >> 4;

    __shared__ __align__(16) _Float16 mg_s[4608];

    const int nbase = n0 + w * 32;
    float qfr[2][8];
#pragma unroll
    for (int rt = 0; rt < 2; rt++) {
        const int n = nbase + rt * 16 + l15;
        const float* qp = qf + (size_t)n * 256 + h * 32 + quad * 8;
#pragma unroll
        for (int j = 0; j < 8; j++) qfr[rt][j] = qp[j];
    }
    float4v acc[2][9];
#pragma unroll
    for (int rt = 0; rt < 2; rt++)
#pragma unroll
        for (int ct = 0; ct < 9; ct++) acc[rt][ct] = float4v{0.f, 0.f, 0.f, 0.f};

    const int kt0 = slice * 100;
    for (int kt = kt0; kt < kt0 + 100; kt++) {
        __syncthreads();
        // stage MG slab (9216 B) into LDS
        {
            const uint4* src = (const uint4*)(MG + ((size_t)kt * 8 + h) * 4608);
            uint4* dstl = (uint4*)mg_s;
            for (int i = tid; i < 576; i += 256) dstl[i] = src[i];
        }
        __syncthreads();
        // A fragments: trig[kkut][n] * qf[n][d],  d = quad*8+j
        half8 af[2];
#pragma unroll
        for (int rt = 0; rt < 2; rt++) {
            const float tv = (float)trig16[(size_t)kt * 2048 + nbase + rt * 16 + l15];
#pragma unroll
            for (int j = 0; j < 8; j++) af[rt][j] = (_Float16)(tv * qfr[rt][j]);
        }
#pragma unroll
        for (int ct = 0; ct < 9; ct++) {
            const half8 b = *(const half8*)&mg_s[quad * 1152 + (ct * 16 + l15) * 8];
            acc[0][ct] = __builtin_amdgcn_mfma_f32_16x16x32_f16(af[0], b, acc[0][ct], 0, 0, 0);
            acc[1][ct] = __builtin_amdgcn_mfma_f32_16x16x32_f16(af[1], b, acc[1][ct], 0, 0, 0);
        }
    }
    // epilogue: atomic-add partials into outm[n][m][h][c]
#pragma unroll
    for (int rt = 0; rt < 2; rt++)
#pragma unroll
        for (int ct = 0; ct < 9; ct++) {
#pragma unroll
            for (int r = 0; r < 4; r++) {
                const int n = nbase + rt * 16 + quad * 4 + r;
                const int cm = ct * 16 + l15;
                const int c = cm / 9, m = cm - c * 9;
                atomicAdd(&outm[((size_t)n * 9 + m) * 128 + h * 16 + c], acc[rt][ct][r]);
            }
        }
}

// ================================ launcher =================================
extern "C" void kernel_launch(void* const* d_in, const int* in_sizes, int n_in,
                              void* d_out, int out_size, void* d_ws, size_t ws_size,
                              hipStream_t stream) {
    const float* pos  = (const float*)d_in[0];
    const float* feat = (const float*)d_in[1];
    const float* Wq   = (const float*)d_in[2];
    const float* Wk   = (const float*)d_in[3];
    const float* Wv   = (const float*)d_in[4];
    const float* Wo   = (const float*)d_in[5];
    const float* a    = (const float*)d_in[6];
    const float* kap  = (const float*)d_in[7];
    float* out = (float*)d_out;
    float* ws = (float*)d_ws;

    // float-slot layout (~83.6 MB total)
    float* qf    = ws;                    // 524288
    float* kf    = qf + 524288;           // 524288
    float* v     = kf + 524288;           // 2359296
    float* trigF = v + 2359296;           // 524288 slots = trig16 f16[512*2048]
    float* ksum  = trigF + 524288;        // 256
    float* rz    = ksum + 256;            // 16384
    float* G     = rz + 16384;            // 129600
    float* M16F  = G + 129600;            // 9437184 slots = M16 f16[512*8*4608]; outm overlays first 2359296
    float* regX  = M16F + 9437184;        // 7372800 slots: R (first 1572864), later MG f16[400*8*4608]
    float* R     = regX;
    float* outm  = M16F;                  // overlay: M16 dead after fold_k
    _Float16* trig16 = (_Float16*)trigF;
    _Float16* M16    = (_Float16*)M16F;
    _Float16* MG16   = (_Float16*)regX;

    const float* cst = d_const_g;

    hipLaunchKernelGGL(radial_k, dim3(2048), dim3(256), 0, stream, feat, R);
    hipLaunchKernelGGL(gemm_k, dim3(4, 32), dim3(256), 0, stream, R, Wq, qf, 2048, 256, 768, 1, rz);
    hipLaunchKernelGGL(gemm_k, dim3(4, 32), dim3(256), 0, stream, R, Wk, kf, 2048, 256, 768, 1, rz);
    hipLaunchKernelGGL(gemm_k, dim3(2, 288), dim3(256), 0, stream, feat, Wv, v, 18432, 128, 256, 2, rz);
    hipMemsetAsync(trigF, 0, 524288 * sizeof(float), stream);   // zero pad rows 400..511
    hipLaunchKernelGGL(trig_k, dim3(2048), dim3(256), 0, stream, pos, kap, cst, trig16);
    hipLaunchKernelGGL(ksum_k, dim3(1), dim3(256), 0, stream, kf, ksum);
    hipLaunchKernelGGL(z_k, dim3(64), dim3(256), 0, stream, qf, ksum, rz);
    hipLaunchKernelGGL(g_k, dim3(64), dim3(256), 0, stream, a, cst, G);
    hipLaunchKernelGGL(multipole_mm_k, dim3(72, 4, 8), dim3(256), 0, stream, trig16, kf, v, M16);
    hipLaunchKernelGGL(fold_k, dim3(400, 8), dim3(256), 0, stream, M16, G, MG16);
    hipMemsetAsync(outm, 0, 2359296 * sizeof(float), stream);   // after fold_k (stream-ordered)
    hipLaunchKernelGGL(mm_local_k, dim3(16, 8, 4), dim3(256), 0, stream, qf, trig16, MG16, outm);
    hipLaunchKernelGGL(gemm_k, dim3(4, 288), dim3(256), 0, stream, outm, Wo, out, 18432, 256, 128, 3, rz);
}

// Round 4
// 592.532 us; speedup vs baseline: 5.2161x; 1.5477x over previous
//
#include <hip/hip_runtime.h>
#include <cmath>
#include <complex>
#include <algorithm>

// ---------------------------------------------------------------------------
// Problem constants: LMAX=2, NC=9, H=8, DQK=32, CV=16, K=8, U=25, N=2048, C=256
// ---------------------------------------------------------------------------

typedef _Float16 half8 __attribute__((ext_vector_type(8)));
typedef _Float16 half4v __attribute__((ext_vector_type(4)));
typedef float float4v __attribute__((ext_vector_type(4)));

// ========================= host-side constant tables ========================
namespace {

using cd = std::complex<double>;

static double fct(int n) { double r = 1.0; for (int i = 2; i <= n; ++i) r *= i; return r; }

static double cg_coef(int j1, int m1, int j2, int m2, int j, int m) {
    if (m1 + m2 != m || j < std::abs(j1 - j2) || j > j1 + j2) return 0.0;
    double pref = std::sqrt((2 * j + 1) * fct(j + j1 - j2) * fct(j - j1 + j2) * fct(j1 + j2 - j) / fct(j1 + j2 + j + 1));
    pref *= std::sqrt(fct(j + m) * fct(j - m) * fct(j1 - m1) * fct(j1 + m1) * fct(j2 - m2) * fct(j2 + m2));
    double s = 0.0;
    for (int k = 0; k <= j1 + j2 - j; ++k) {
        int d0 = k, d1 = j1 + j2 - j - k, d2 = j1 - m1 - k, d3 = j2 + m2 - k, d4 = j - j2 + m1 + k, d5 = j - j1 - m2 + k;
        if (d0 < 0 || d1 < 0 || d2 < 0 || d3 < 0 || d4 < 0 || d5 < 0) continue;
        s += ((k & 1) ? -1.0 : 1.0) / (fct(d0) * fct(d1) * fct(d2) * fct(d3) * fct(d4) * fct(d5));
    }
    return pref * s;
}

static void umat(int l, cd u[5][5]) {
    for (int i = 0; i < 5; i++) for (int j = 0; j < 5; j++) u[i][j] = cd(0, 0);
    const double s = 1.0 / std::sqrt(2.0);
    for (int m = -l; m <= l; m++) {
        double sgn = (std::abs(m) & 1) ? -1.0 : 1.0;   // (-1)^m
        if (m > 0)      { u[l + m][l + m] = cd(sgn * s, 0); u[l + m][l - m] = cd(s, 0); }
        else if (m == 0){ u[l][l] = cd(1, 0); }
        else            { u[l + m][l + m] = cd(0, s);       u[l + m][l - m] = cd(0, -sgn * s); }
    }
}

static void real_cg_f(int l1, int l2, int L, double out[5][5][5]) {
    cd U1[5][5], U2[5][5], UL[5][5];
    umat(l1, U1); umat(l2, U2); umat(L, UL);
    const int n1 = 2 * l1 + 1, n2 = 2 * l2 + 1, n3 = 2 * L + 1;
    double cgt[5][5][5];
    for (int i1 = 0; i1 < n1; i1++) for (int i2 = 0; i2 < n2; i2++) for (int i3 = 0; i3 < n3; i3++)
        cgt[i1][i2][i3] = cg_coef(l1, i1 - l1, l2, i2 - l2, L, i3 - L);
    cd r[5][5][5];
    double nr = 0, ni = 0;
    for (int a1 = 0; a1 < n1; a1++) for (int b = 0; b < n2; b++) for (int c = 0; c < n3; c++) {
        cd acc(0, 0);
        for (int uu = 0; uu < n1; uu++) for (int vv = 0; vv < n2; vv++) for (int w = 0; w < n3; w++) {
            double cval = cgt[uu][vv][w];
            if (cval == 0.0) continue;
            acc += U1[a1][uu] * U2[b][vv] * std::conj(UL[c][w]) * cval;
        }
        r[a1][b][c] = acc;
        nr += acc.real() * acc.real();
        ni += acc.imag() * acc.imag();
    }
    const bool useRe = std::sqrt(nr) >= std::sqrt(ni);
    for (int a1 = 0; a1 < n1; a1++) for (int b = 0; b < n2; b++) for (int c = 0; c < n3; c++)
        out[a1][b][c] = useRe ? r[a1][b][c].real() : r[a1][b][c].imag();
}

// device constant buffer layout: YW[9*25] | RRED[9*81] | DIRS[25*3]  = 1029 floats
static float  h_const[1029];
static float* d_const_g = nullptr;

struct GlobalInit {
    GlobalInit() {
        const double PI = 3.14159265358979323846;
        const double gx[5] = {-0.9061798459386640, -0.5384693101056831, 0.0, 0.5384693101056831, 0.9061798459386640};
        const double gw[5] = { 0.23692688505618908, 0.47862867049936647, 0.5688888888888889, 0.47862867049936647, 0.23692688505618908};
        double YW[9][25], DIRS[25][3];
        for (int u = 0; u < 25; ++u) {
            const int it = u / 5, ip = u % 5;
            const double ct = gx[it], wq = gw[it] * (2.0 * PI / 5.0), ph = 2.0 * PI * ip / 5.0;
            const double st = std::sqrt(std::max(1.0 - ct * ct, 0.0));
            const double x = st * std::cos(ph), y = st * std::sin(ph), z = ct;
            DIRS[u][0] = x; DIRS[u][1] = y; DIRS[u][2] = z;
            double Y[9];
            Y[0] = 0.282095;           Y[1] = 0.488603 * y;      Y[2] = 0.488603 * z;
            Y[3] = 0.488603 * x;       Y[4] = 1.092548 * x * y;  Y[5] = 1.092548 * y * z;
            Y[6] = 0.315392 * (3 * z * z - 1); Y[7] = 1.092548 * x * z; Y[8] = 0.546274 * (x * x - y * y);
            for (int e = 0; e < 9; e++) YW[e][u] = Y[e] * wq;
        }
        double RRED[9][9][9];
        for (int i = 0; i < 9; i++) for (int j = 0; j < 9; j++) for (int k = 0; k < 9; k++) RRED[i][j][k] = 0.0;
        const int off[3] = {0, 1, 4};
        double cnt[3] = {0, 0, 0};
        double rc[5][5][5];
        for (int l1 = 0; l1 <= 2; l1++) for (int l2 = 0; l2 <= 2; l2++) {
            const int Llo = std::abs(l1 - l2), Lhi = std::min(l1 + l2, 2);
            for (int L = Llo; L <= Lhi; L++) {
                real_cg_f(l1, l2, L, rc);
                for (int i1 = 0; i1 < 2 * l1 + 1; i1++)
                    for (int i2 = 0; i2 < 2 * l2 + 1; i2++)
                        for (int i3 = 0; i3 < 2 * L + 1; i3++)
                            RRED[off[l1] + i1][off[l2] + i2][off[L] + i3] += rc[i1][i2][i3];
                cnt[L] += 1.0;
            }
        }
        for (int L = 0; L <= 2; L++) {
            const double dv = std::max(cnt[L], 1.0);
            for (int a1 = 0; a1 < 9; a1++) for (int b = 0; b < 9; b++)
                for (int k = 0; k < 2 * L + 1; k++) RRED[a1][b][off[L] + k] /= dv;
        }
        for (int e = 0; e < 9; e++) for (int u = 0; u < 25; u++) h_const[e * 25 + u] = (float)YW[e][u];
        for (int e = 0; e < 9; e++) for (int l = 0; l < 9; l++) for (int m = 0; m < 9; m++)
            h_const[225 + e * 81 + l * 9 + m] = (float)RRED[e][l][m];
        for (int u = 0; u < 25; u++) for (int ax = 0; ax < 3; ax++) h_const[954 + u * 3 + ax] = (float)DIRS[u][ax];
        if (hipMalloc((void**)&d_const_g, 1029 * sizeof(float)) == hipSuccess)
            hipMemcpy(d_const_g, h_const, 1029 * sizeof(float), hipMemcpyHostToDevice);
    }
} g_init;

} // namespace

// ============================== device kernels ==============================

// R[n][p][c]: p=0 -> feat(l=0); p=1 -> |l=1 block|; p=2 -> |l=2 block|
__global__ void radial_k(const float* __restrict__ feat, float* __restrict__ R) {
    const int n = blockIdx.x, c = threadIdx.x;
    const float* f = feat + (size_t)n * 9 * 256 + c;
    const float f0 = f[0];
    const float a1 = f[256], a2 = f[512], a3 = f[768];
    const float b1 = f[1024], b2 = f[1280], b3 = f[1536], b4 = f[1792], b5 = f[2048];
    const float r1 = sqrtf(a1 * a1 + a2 * a2 + a3 * a3 + 1e-8f);
    const float r2 = sqrtf(b1 * b1 + b2 * b2 + b3 * b3 + b4 * b4 + b5 * b5 + 1e-8f);
    float* o = R + (size_t)n * 768 + c;
    o[0] = f0; o[256] = r1; o[512] = r2;
}

// generic 64x64-tile f32 GEMM, C = A(MxK) @ B(KxN)
// mode 0 plain, 1 elu+1, 2 v-scatter, 4 sum-4-partials A with rZ[n][h] scale
__global__ __launch_bounds__(256) void gemm_k(const float* __restrict__ A, const float* __restrict__ B,
                                              float* __restrict__ Cv, int M, int N, int Kd, int mode,
                                              const float* __restrict__ rZ) {
    __shared__ float As[32][68];   // [k][row]
    __shared__ float Bs[32][68];   // [k][col]
    const int tid = threadIdx.x;
    const int tx = tid & 15, ty = tid >> 4;
    const int rb = blockIdx.y * 64, cb = blockIdx.x * 64;
    float acc[4][4];
#pragma unroll
    for (int i = 0; i < 4; i++) for (int j = 0; j < 4; j++) acc[i][j] = 0.f;
    for (int k0 = 0; k0 < Kd; k0 += 32) {
        __syncthreads();
#pragma unroll
        for (int i = 0; i < 2; i++) {
            const int idx = tid + i * 256;
            const int row = idx >> 3, kq = idx & 7;
            float4 av;
            if (mode == 4) {
                const float* Ap = A + (size_t)(rb + row) * Kd + k0 + kq * 4;
                const float4 a0 = *(const float4*)(Ap);
                const float4 a1 = *(const float4*)(Ap + 2359296);
                const float4 a2 = *(const float4*)(Ap + 4718592);
                const float4 a3 = *(const float4*)(Ap + 7077888);
                av.x = a0.x + a1.x + a2.x + a3.x;
                av.y = a0.y + a1.y + a2.y + a3.y;
                av.z = a0.z + a1.z + a2.z + a3.z;
                av.w = a0.w + a1.w + a2.w + a3.w;
                const int n = (rb + row) / 9;
                const int hh = (k0 + kq * 4) >> 4;
                const float rz = rZ[n * 8 + hh];
                av.x *= rz; av.y *= rz; av.z *= rz; av.w *= rz;
            } else {
                av = *(const float4*)(A + (size_t)(rb + row) * Kd + k0 + kq * 4);
            }
            As[kq * 4 + 0][row] = av.x; As[kq * 4 + 1][row] = av.y;
            As[kq * 4 + 2][row] = av.z; As[kq * 4 + 3][row] = av.w;
        }
#pragma unroll
        for (int i = 0; i < 2; i++) {
            const int idx = tid + i * 256;
            const int kr = idx >> 4, cq = idx & 15;
            *(float4*)&Bs[kr][cq * 4] = *(const float4*)(B + (size_t)(k0 + kr) * N + cb + cq * 4);
        }
        __syncthreads();
#pragma unroll 8
        for (int k = 0; k < 32; k++) {
            const float4 a = *(const float4*)&As[k][ty * 4];
            const float4 b = *(const float4*)&Bs[k][tx * 4];
            const float av[4] = {a.x, a.y, a.z, a.w};
            const float bv[4] = {b.x, b.y, b.z, b.w};
#pragma unroll
            for (int i = 0; i < 4; i++)
#pragma unroll
                for (int j = 0; j < 4; j++) acc[i][j] += av[i] * bv[j];
        }
    }
#pragma unroll
    for (int i = 0; i < 4; i++) {
        const int r = rb + ty * 4 + i;
#pragma unroll
        for (int j = 0; j < 4; j++) {
            const int cc2 = cb + tx * 4 + j;
            float val = acc[i][j];
            if (mode == 1) val = (val > 0.f ? val : expf(val) - 1.f) + 1.f;
            if (mode == 2) {
                const int n = r / 9, l = r - n * 9, hq = cc2 >> 4, cvq = cc2 & 15;
                Cv[(((size_t)n * 8 + hq) * 16 + cvq) * 9 + l] = val;   // v[n][h][c][l]
            } else {
                Cv[(size_t)r * N + cc2] = val;
            }
        }
    }
}

// trig16[kkut][n] (f16) = cos/sin(kappa_kk * pos_n . dir_u); kkut = (kk*25+u)*2 + t
__global__ void trig_k(const float* __restrict__ pos, const float* __restrict__ kappa,
                       const float* __restrict__ cst, _Float16* __restrict__ trig16) {
    const int n = blockIdx.x, t = threadIdx.x;
    if (t >= 200) return;
    const int kq = t / 25, u = t - kq * 25;
    const float* dirs = cst + 954;
    const float ph = kappa[kq] * (pos[n * 3] * dirs[u * 3] + pos[n * 3 + 1] * dirs[u * 3 + 1] + pos[n * 3 + 2] * dirs[u * 3 + 2]);
    float s, c;
    sincosf(ph, &s, &c);
    const int kkut = (kq * 25 + u) * 2;
    trig16[(size_t)kkut * 2048 + n] = (_Float16)c;
    trig16[(size_t)(kkut + 1) * 2048 + n] = (_Float16)s;
}

__global__ void ksum_k(const float* __restrict__ kf, float* __restrict__ ksum) {
    const int j = threadIdx.x;   // 256
    float s0 = 0, s1 = 0, s2 = 0, s3 = 0;
    for (int n = 0; n < 2048; n += 4) {
        s0 += kf[(size_t)n * 256 + j];
        s1 += kf[(size_t)(n + 1) * 256 + j];
        s2 += kf[(size_t)(n + 2) * 256 + j];
        s3 += kf[(size_t)(n + 3) * 256 + j];
    }
    ksum[j] = s0 + s1 + s2 + s3;
}

// rz[n][h] = 1 / (qf[n,h,:].ksum[h,:] + 1e-6)
__global__ void z_k(const float* __restrict__ qf, const float* __restrict__ ksum, float* __restrict__ rz) {
    const int idx = blockIdx.x * 256 + threadIdx.x;   // N*H = 16384
    const int n = idx >> 3, h = idx & 7;
    float s = 0.f;
#pragma unroll
    for (int d = 0; d < 32; d++) s += qf[(size_t)n * 256 + h * 32 + d] * ksum[h * 32 + d];
    rz[idx] = 1.0f / (s + 1e-6f);
}

// G[kk][h][u][l*9+m] = sum_e aE[e,h,kk] * YW[e,u] * RRED[e,l,m]
__global__ void g_k(const float* __restrict__ a, const float* __restrict__ cst, float* __restrict__ G) {
    const int kk = blockIdx.x & 7, h = blockIdx.x >> 3;
    __shared__ float ae[9];
    if (threadIdx.x < 9) {
        const int ldeg[9] = {0, 1, 1, 1, 2, 2, 2, 2, 2};
        ae[threadIdx.x] = a[ldeg[threadIdx.x] * 64 + h * 8 + kk];
    }
    __syncthreads();
    const float* yw = cst;
    const float* rred = cst + 225;
    for (int i = threadIdx.x; i < 25 * 81; i += 256) {
        const int u = i / 81, lm = i - u * 81;
        float s = 0.f;
#pragma unroll
        for (int e = 0; e < 9; e++) s += ae[e] * yw[e * 25 + u] * rred[e * 81 + lm];
        G[((size_t)(kk * 8 + h) * 25 + u) * 81 + lm] = s;
    }
}

// MFMA multipole: per h, M16[kkut][h][j] = sum_n trig16[kkut][n] * W[n][j],
//   j = cl*32 + d,  W[n][cl*32+d] = kf[n,h,d] * v[n,h,cl]
// tile: 128 rows (kkut, padded to 512) x 64 cols (2 cl x 32 d); 4 row-split waves
__global__ __launch_bounds__(256) void multipole_mm_k(const _Float16* __restrict__ trig16,
                                                      const float* __restrict__ kf,
                                                      const float* __restrict__ v,
                                                      _Float16* __restrict__ M16) {
    const int cl0 = blockIdx.x * 2;          // 2 cl values per block
    const int cb  = blockIdx.x * 64;         // global col base
    const int rb  = blockIdx.y * 128;        // kkut row base (rows padded to 512)
    const int h   = blockIdx.z;
    const int tid = threadIdx.x;
    const int w = tid >> 6, lane = tid & 63;
    const int l15 = lane & 15, quad = lane >> 4;

    __shared__ __align__(16) _Float16 Ws[64 * 40];   // [col][n], row stride 40 f16 (80 B)

    float4v acc[2][4];
#pragma unroll
    for (int rt = 0; rt < 2; rt++)
#pragma unroll
        for (int s = 0; s < 4; s++) acc[rt][s] = float4v{0.f, 0.f, 0.f, 0.f};

    const int r0 = rb + w * 32;
    const int sn = tid >> 3, sq = tid & 7;   // stager: n-row, d-quartet

    for (int nb = 0; nb < 2048; nb += 32) {
        // ---- stage + build W tile (from registers, no kf round-trip) ----
        const float4 kv = *(const float4*)(kf + (size_t)(nb + sn) * 256 + h * 32 + sq * 4);
        const float v0 = v[((size_t)(nb + sn) * 8 + h) * 144 + cl0];
        const float v1 = v[((size_t)(nb + sn) * 8 + h) * 144 + cl0 + 1];
        __syncthreads();   // protect Ws against previous iteration's readers
        {
            const int d0 = sq * 4;
            // cl slot 0: cols d0..d0+3 ; cl slot 1: cols 32+d0..32+d0+3
            Ws[(d0 + 0) * 40 + sn] = (_Float16)(kv.x * v0);
            Ws[(d0 + 1) * 40 + sn] = (_Float16)(kv.y * v0);
            Ws[(d0 + 2) * 40 + sn] = (_Float16)(kv.z * v0);
            Ws[(d0 + 3) * 40 + sn] = (_Float16)(kv.w * v0);
            Ws[(32 + d0 + 0) * 40 + sn] = (_Float16)(kv.x * v1);
            Ws[(32 + d0 + 1) * 40 + sn] = (_Float16)(kv.y * v1);
            Ws[(32 + d0 + 2) * 40 + sn] = (_Float16)(kv.z * v1);
            Ws[(32 + d0 + 3) * 40 + sn] = (_Float16)(kv.w * v1);
        }
        __syncthreads();
        // ---- A fragments (direct f16 global, L2-resident trig16) ----
        half8 af[2];
#pragma unroll
        for (int rt = 0; rt < 2; rt++)
            af[rt] = *(const half8*)(trig16 + (size_t)(r0 + rt * 16 + l15) * 2048 + nb + quad * 8);
        // ---- MFMA over 4 col-subtiles ----
#pragma unroll
        for (int s = 0; s < 4; s++) {
            const half8 b = *(const half8*)&Ws[(s * 16 + l15) * 40 + quad * 8];
            acc[0][s] = __builtin_amdgcn_mfma_f32_16x16x32_f16(af[0], b, acc[0][s], 0, 0, 0);
            acc[1][s] = __builtin_amdgcn_mfma_f32_16x16x32_f16(af[1], b, acc[1][s], 0, 0, 0);
        }
    }
    // epilogue: C fragment (col=lane&15, row=quad*4+reg) -> M16[kkut][h][col]
#pragma unroll
    for (int rt = 0; rt < 2; rt++)
#pragma unroll
        for (int s = 0; s < 4; s++)
#pragma unroll
            for (int r = 0; r < 4; r++) {
                const int row = r0 + rt * 16 + quad * 4 + r;
                const int col = cb + s * 16 + l15;
                M16[((size_t)row * 8 + h) * 4608 + col] = (_Float16)acc[rt][s][r];
            }
}

// MG[kkut][h][quad][cm][8j] (f16) = sum_l M16[kkut][h][(c*9+l)*32+d] * G[kk,h,u][l*9+m]
//   cm = c*9+m, d = quad*8+j
__global__ __launch_bounds__(256) void fold_k(const _Float16* __restrict__ Mv, const float* __restrict__ G,
                                              _Float16* __restrict__ MG) {
    const int kt = blockIdx.x, h = blockIdx.y;
    const int tid = threadIdx.x;
    __shared__ float ms[144 * 33];   // [cl][d] padded 33
    __shared__ float gs[81];
    const _Float16* src = Mv + ((size_t)kt * 8 + h) * 4608;
    for (int i = tid; i < 4608; i += 256) {
        const int cl = i >> 5, d = i & 31;
        ms[cl * 33 + d] = (float)src[i];
    }
    const int kk = kt / 50, u = (kt >> 1) % 25;
    if (tid < 81) gs[tid] = G[(((size_t)kk * 8 + h) * 25 + u) * 81 + tid];
    __syncthreads();
    _Float16* dst = MG + ((size_t)kt * 8 + h) * 4608;
    for (int i = tid; i < 4608; i += 256) {
        const int quad = i / 1152, r = i - quad * 1152;
        const int cm = r >> 3, j = r & 7;
        const int d = quad * 8 + j, c = cm / 9, m = cm - c * 9;
        float s = 0.f;
#pragma unroll
        for (int l = 0; l < 9; l++) s += ms[(c * 9 + l) * 33 + d] * gs[l * 9 + m];
        dst[i] = (_Float16)s;
    }
}

// local stage via MFMA, barrier-free: B-fragments are direct b128 global loads
// (MG layout == fragment layout); partials stored per kt-slice, no atomics.
// grid (16 ngroups, 8 h, 4 slices); block 256 = 4 waves; wave: 32 n x 144 cm
__global__ __launch_bounds__(256) void mm_local_k(const float* __restrict__ qf, const _Float16* __restrict__ trig16,
                                                  const _Float16* __restrict__ MG, float* __restrict__ outp) {
    const int h = blockIdx.y;
    const int n0 = blockIdx.x * 128;
    const int slice = blockIdx.z;
    const int tid = threadIdx.x;
    const int w = tid >> 6, lane = tid & 63;
    const int l15 = lane & 15, quad = lane >> 4;

    const int nbase = n0 + w * 32;
    float qfr[2][8];
#pragma unroll
    for (int rt = 0; rt < 2; rt++) {
        const int n = nbase + rt * 16 + l15;
        const float* qp = qf + (size_t)n * 256 + h * 32 + quad * 8;
#pragma unroll
        for (int j = 0; j < 8; j++) qfr[rt][j] = qp[j];
    }
    float4v acc[2][9];
#pragma unroll
    for (int rt = 0; rt < 2; rt++)
#pragma unroll
        for (int ct = 0; ct < 9; ct++) acc[rt][ct] = float4v{0.f, 0.f, 0.f, 0.f};

    const int kt0 = slice * 100;
    const _Float16* slab0 = MG + (((size_t)kt0 * 8 + h) * 4608) + quad * 1152 + l15 * 8;
    const _Float16* trg0  = trig16 + (size_t)kt0 * 2048 + nbase + l15;

    for (int kt = 0; kt < 100; kt++) {
        const _Float16* slab = slab0 + (size_t)kt * 8 * 4608;
        // A fragments: trig[kkut][n] * qf[n][d],  d = quad*8+j
        const float tv0 = (float)trg0[(size_t)kt * 2048];
        const float tv1 = (float)trg0[(size_t)kt * 2048 + 16];
        half8 af[2];
#pragma unroll
        for (int j = 0; j < 8; j++) af[0][j] = (_Float16)(tv0 * qfr[0][j]);
#pragma unroll
        for (int j = 0; j < 8; j++) af[1][j] = (_Float16)(tv1 * qfr[1][j]);
#pragma unroll
        for (int ct = 0; ct < 9; ct++) {
            const half8 b = *(const half8*)(slab + ct * 128);
            acc[0][ct] = __builtin_amdgcn_mfma_f32_16x16x32_f16(af[0], b, acc[0][ct], 0, 0, 0);
            acc[1][ct] = __builtin_amdgcn_mfma_f32_16x16x32_f16(af[1], b, acc[1][ct], 0, 0, 0);
        }
    }
    // epilogue: direct stores into this slice's partial buffer outp[slice][n][m][h][c]
    float* dst = outp + (size_t)slice * 2359296;
#pragma unroll
    for (int rt = 0; rt < 2; rt++)
#pragma unroll
        for (int ct = 0; ct < 9; ct++) {
#pragma unroll
            for (int r = 0; r < 4; r++) {
                const int n = nbase + rt * 16 + quad * 4 + r;
                const int cm = ct * 16 + l15;
                const int c = cm / 9, m = cm - c * 9;
                dst[((size_t)n * 9 + m) * 128 + h * 16 + c] = acc[rt][ct][r];
            }
        }
}

// ================================ launcher =================================
extern "C" void kernel_launch(void* const* d_in, const int* in_sizes, int n_in,
                              void* d_out, int out_size, void* d_ws, size_t ws_size,
                              hipStream_t stream) {
    const float* pos  = (const float*)d_in[0];
    const float* feat = (const float*)d_in[1];
    const float* Wq   = (const float*)d_in[2];
    const float* Wk   = (const float*)d_in[3];
    const float* Wv   = (const float*)d_in[4];
    const float* Wo   = (const float*)d_in[5];
    const float* a    = (const float*)d_in[6];
    const float* kap  = (const float*)d_in[7];
    float* out = (float*)d_out;
    float* ws = (float*)d_ws;

    // float-slot layout (~83.6 MB total)
    float* qf    = ws;                    // 524288
    float* kf    = qf + 524288;           // 524288
    float* v     = kf + 524288;           // 2359296
    float* trigF = v + 2359296;           // 524288 slots = trig16 f16[512*2048]
    float* ksum  = trigF + 524288;        // 256
    float* rz    = ksum + 256;            // 16384
    float* G     = rz + 16384;            // 129600
    float* M16F  = G + 129600;            // 9437184 slots = M16 f16[512*8*4608]; later outp[4][2359296]
    float* regX  = M16F + 9437184;        // 7372800 slots: R (first 1572864), later MG f16[400*8*4608]
    float* R     = regX;
    float* outp  = M16F;                  // overlay: M16 dead after fold_k; 4 partial buffers
    _Float16* trig16 = (_Float16*)trigF;
    _Float16* M16    = (_Float16*)M16F;
    _Float16* MG16   = (_Float16*)regX;

    const float* cst = d_const_g;

    hipLaunchKernelGGL(radial_k, dim3(2048), dim3(256), 0, stream, feat, R);
    hipLaunchKernelGGL(gemm_k, dim3(4, 32), dim3(256), 0, stream, R, Wq, qf, 2048, 256, 768, 1, rz);
    hipLaunchKernelGGL(gemm_k, dim3(4, 32), dim3(256), 0, stream, R, Wk, kf, 2048, 256, 768, 1, rz);
    hipLaunchKernelGGL(gemm_k, dim3(2, 288), dim3(256), 0, stream, feat, Wv, v, 18432, 128, 256, 2, rz);
    hipMemsetAsync(trigF, 0, 524288 * sizeof(float), stream);   // zero pad rows 400..511
    hipLaunchKernelGGL(trig_k, dim3(2048), dim3(256), 0, stream, pos, kap, cst, trig16);
    hipLaunchKernelGGL(ksum_k, dim3(1), dim3(256), 0, stream, kf, ksum);
    hipLaunchKernelGGL(z_k, dim3(64), dim3(256), 0, stream, qf, ksum, rz);
    hipLaunchKernelGGL(g_k, dim3(64), dim3(256), 0, stream, a, cst, G);
    hipLaunchKernelGGL(multipole_mm_k, dim3(72, 4, 8), dim3(256), 0, stream, trig16, kf, v, M16);
    hipLaunchKernelGGL(fold_k, dim3(400, 8), dim3(256), 0, stream, M16, G, MG16);
    hipLaunchKernelGGL(mm_local_k, dim3(16, 8, 4), dim3(256), 0, stream, qf, trig16, MG16, outp);
    hipLaunchKernelGGL(gemm_k, dim3(4, 288), dim3(256), 0, stream, outp, Wo, out, 18432, 256, 128, 4, rz);
}

// Round 5
// 575.926 us; speedup vs baseline: 5.3665x; 1.0288x over previous
//
#include <hip/hip_runtime.h>
#include <cmath>
#include <complex>
#include <algorithm>

// ---------------------------------------------------------------------------
// Problem constants: LMAX=2, NC=9, H=8, DQK=32, CV=16, K=8, U=25, N=2048, C=256
// ---------------------------------------------------------------------------

typedef _Float16 half8 __attribute__((ext_vector_type(8)));
typedef _Float16 half4v __attribute__((ext_vector_type(4)));
typedef float float4v __attribute__((ext_vector_type(4)));

// ========================= host-side constant tables ========================
namespace {

using cd = std::complex<double>;

static double fct(int n) { double r = 1.0; for (int i = 2; i <= n; ++i) r *= i; return r; }

static double cg_coef(int j1, int m1, int j2, int m2, int j, int m) {
    if (m1 + m2 != m || j < std::abs(j1 - j2) || j > j1 + j2) return 0.0;
    double pref = std::sqrt((2 * j + 1) * fct(j + j1 - j2) * fct(j - j1 + j2) * fct(j1 + j2 - j) / fct(j1 + j2 + j + 1));
    pref *= std::sqrt(fct(j + m) * fct(j - m) * fct(j1 - m1) * fct(j1 + m1) * fct(j2 - m2) * fct(j2 + m2));
    double s = 0.0;
    for (int k = 0; k <= j1 + j2 - j; ++k) {
        int d0 = k, d1 = j1 + j2 - j - k, d2 = j1 - m1 - k, d3 = j2 + m2 - k, d4 = j - j2 + m1 + k, d5 = j - j1 - m2 + k;
        if (d0 < 0 || d1 < 0 || d2 < 0 || d3 < 0 || d4 < 0 || d5 < 0) continue;
        s += ((k & 1) ? -1.0 : 1.0) / (fct(d0) * fct(d1) * fct(d2) * fct(d3) * fct(d4) * fct(d5));
    }
    return pref * s;
}

static void umat(int l, cd u[5][5]) {
    for (int i = 0; i < 5; i++) for (int j = 0; j < 5; j++) u[i][j] = cd(0, 0);
    const double s = 1.0 / std::sqrt(2.0);
    for (int m = -l; m <= l; m++) {
        double sgn = (std::abs(m) & 1) ? -1.0 : 1.0;   // (-1)^m
        if (m > 0)      { u[l + m][l + m] = cd(sgn * s, 0); u[l + m][l - m] = cd(s, 0); }
        else if (m == 0){ u[l][l] = cd(1, 0); }
        else            { u[l + m][l + m] = cd(0, s);       u[l + m][l - m] = cd(0, -sgn * s); }
    }
}

static void real_cg_f(int l1, int l2, int L, double out[5][5][5]) {
    cd U1[5][5], U2[5][5], UL[5][5];
    umat(l1, U1); umat(l2, U2); umat(L, UL);
    const int n1 = 2 * l1 + 1, n2 = 2 * l2 + 1, n3 = 2 * L + 1;
    double cgt[5][5][5];
    for (int i1 = 0; i1 < n1; i1++) for (int i2 = 0; i2 < n2; i2++) for (int i3 = 0; i3 < n3; i3++)
        cgt[i1][i2][i3] = cg_coef(l1, i1 - l1, l2, i2 - l2, L, i3 - L);
    cd r[5][5][5];
    double nr = 0, ni = 0;
    for (int a1 = 0; a1 < n1; a1++) for (int b = 0; b < n2; b++) for (int c = 0; c < n3; c++) {
        cd acc(0, 0);
        for (int uu = 0; uu < n1; uu++) for (int vv = 0; vv < n2; vv++) for (int w = 0; w < n3; w++) {
            double cval = cgt[uu][vv][w];
            if (cval == 0.0) continue;
            acc += U1[a1][uu] * U2[b][vv] * std::conj(UL[c][w]) * cval;
        }
        r[a1][b][c] = acc;
        nr += acc.real() * acc.real();
        ni += acc.imag() * acc.imag();
    }
    const bool useRe = std::sqrt(nr) >= std::sqrt(ni);
    for (int a1 = 0; a1 < n1; a1++) for (int b = 0; b < n2; b++) for (int c = 0; c < n3; c++)
        out[a1][b][c] = useRe ? r[a1][b][c].real() : r[a1][b][c].imag();
}

// device constant buffer layout: YW[9*25] | RRED[9*81] | DIRS[25*3]  = 1029 floats
static float  h_const[1029];
static float* d_const_g = nullptr;

struct GlobalInit {
    GlobalInit() {
        const double PI = 3.14159265358979323846;
        const double gx[5] = {-0.9061798459386640, -0.5384693101056831, 0.0, 0.5384693101056831, 0.9061798459386640};
        const double gw[5] = { 0.23692688505618908, 0.47862867049936647, 0.5688888888888889, 0.47862867049936647, 0.23692688505618908};
        double YW[9][25], DIRS[25][3];
        for (int u = 0; u < 25; ++u) {
            const int it = u / 5, ip = u % 5;
            const double ct = gx[it], wq = gw[it] * (2.0 * PI / 5.0), ph = 2.0 * PI * ip / 5.0;
            const double st = std::sqrt(std::max(1.0 - ct * ct, 0.0));
            const double x = st * std::cos(ph), y = st * std::sin(ph), z = ct;
            DIRS[u][0] = x; DIRS[u][1] = y; DIRS[u][2] = z;
            double Y[9];
            Y[0] = 0.282095;           Y[1] = 0.488603 * y;      Y[2] = 0.488603 * z;
            Y[3] = 0.488603 * x;       Y[4] = 1.092548 * x * y;  Y[5] = 1.092548 * y * z;
            Y[6] = 0.315392 * (3 * z * z - 1); Y[7] = 1.092548 * x * z; Y[8] = 0.546274 * (x * x - y * y);
            for (int e = 0; e < 9; e++) YW[e][u] = Y[e] * wq;
        }
        double RRED[9][9][9];
        for (int i = 0; i < 9; i++) for (int j = 0; j < 9; j++) for (int k = 0; k < 9; k++) RRED[i][j][k] = 0.0;
        const int off[3] = {0, 1, 4};
        double cnt[3] = {0, 0, 0};
        double rc[5][5][5];
        for (int l1 = 0; l1 <= 2; l1++) for (int l2 = 0; l2 <= 2; l2++) {
            const int Llo = std::abs(l1 - l2), Lhi = std::min(l1 + l2, 2);
            for (int L = Llo; L <= Lhi; L++) {
                real_cg_f(l1, l2, L, rc);
                for (int i1 = 0; i1 < 2 * l1 + 1; i1++)
                    for (int i2 = 0; i2 < 2 * l2 + 1; i2++)
                        for (int i3 = 0; i3 < 2 * L + 1; i3++)
                            RRED[off[l1] + i1][off[l2] + i2][off[L] + i3] += rc[i1][i2][i3];
                cnt[L] += 1.0;
            }
        }
        for (int L = 0; L <= 2; L++) {
            const double dv = std::max(cnt[L], 1.0);
            for (int a1 = 0; a1 < 9; a1++) for (int b = 0; b < 9; b++)
                for (int k = 0; k < 2 * L + 1; k++) RRED[a1][b][off[L] + k] /= dv;
        }
        for (int e = 0; e < 9; e++) for (int u = 0; u < 25; u++) h_const[e * 25 + u] = (float)YW[e][u];
        for (int e = 0; e < 9; e++) for (int l = 0; l < 9; l++) for (int m = 0; m < 9; m++)
            h_const[225 + e * 81 + l * 9 + m] = (float)RRED[e][l][m];
        for (int u = 0; u < 25; u++) for (int ax = 0; ax < 3; ax++) h_const[954 + u * 3 + ax] = (float)DIRS[u][ax];
        if (hipMalloc((void**)&d_const_g, 1029 * sizeof(float)) == hipSuccess)
            hipMemcpy(d_const_g, h_const, 1029 * sizeof(float), hipMemcpyHostToDevice);
    }
} g_init;

} // namespace

// ============================== device kernels ==============================

// R[n][p][c]: p=0 -> feat(l=0); p=1 -> |l=1 block|; p=2 -> |l=2 block|
__global__ void radial_k(const float* __restrict__ feat, float* __restrict__ R) {
    const int n = blockIdx.x, c = threadIdx.x;
    const float* f = feat + (size_t)n * 9 * 256 + c;
    const float f0 = f[0];
    const float a1 = f[256], a2 = f[512], a3 = f[768];
    const float b1 = f[1024], b2 = f[1280], b3 = f[1536], b4 = f[1792], b5 = f[2048];
    const float r1 = sqrtf(a1 * a1 + a2 * a2 + a3 * a3 + 1e-8f);
    const float r2 = sqrtf(b1 * b1 + b2 * b2 + b3 * b3 + b4 * b4 + b5 * b5 + 1e-8f);
    float* o = R + (size_t)n * 768 + c;
    o[0] = f0; o[256] = r1; o[512] = r2;
}

// generic 64x64-tile f32 GEMM, C = A(MxK) @ B(KxN)
// mode 0 plain, 1 elu+1, 2 v-scatter f16 transposed, 4 sum-4-partials A with rZ scale,
// 5 elu+1 -> f16 transposed [col][row]
__global__ __launch_bounds__(256) void gemm_k(const float* __restrict__ A, const float* __restrict__ B,
                                              float* __restrict__ Cv, int M, int N, int Kd, int mode,
                                              const float* __restrict__ rZ) {
    __shared__ float As[32][68];   // [k][row]
    __shared__ float Bs[32][68];   // [k][col]
    const int tid = threadIdx.x;
    const int tx = tid & 15, ty = tid >> 4;
    const int rb = blockIdx.y * 64, cb = blockIdx.x * 64;
    float acc[4][4];
#pragma unroll
    for (int i = 0; i < 4; i++) for (int j = 0; j < 4; j++) acc[i][j] = 0.f;
    for (int k0 = 0; k0 < Kd; k0 += 32) {
        __syncthreads();
#pragma unroll
        for (int i = 0; i < 2; i++) {
            const int idx = tid + i * 256;
            const int row = idx >> 3, kq = idx & 7;
            float4 av;
            if (mode == 4) {
                const float* Ap = A + (size_t)(rb + row) * Kd + k0 + kq * 4;
                const float4 a0 = *(const float4*)(Ap);
                const float4 a1 = *(const float4*)(Ap + 2359296);
                const float4 a2 = *(const float4*)(Ap + 4718592);
                const float4 a3 = *(const float4*)(Ap + 7077888);
                av.x = a0.x + a1.x + a2.x + a3.x;
                av.y = a0.y + a1.y + a2.y + a3.y;
                av.z = a0.z + a1.z + a2.z + a3.z;
                av.w = a0.w + a1.w + a2.w + a3.w;
                const int n = (rb + row) / 9;
                const int hh = (k0 + kq * 4) >> 4;
                const float rz = rZ[n * 8 + hh];
                av.x *= rz; av.y *= rz; av.z *= rz; av.w *= rz;
            } else {
                av = *(const float4*)(A + (size_t)(rb + row) * Kd + k0 + kq * 4);
            }
            As[kq * 4 + 0][row] = av.x; As[kq * 4 + 1][row] = av.y;
            As[kq * 4 + 2][row] = av.z; As[kq * 4 + 3][row] = av.w;
        }
#pragma unroll
        for (int i = 0; i < 2; i++) {
            const int idx = tid + i * 256;
            const int kr = idx >> 4, cq = idx & 15;
            *(float4*)&Bs[kr][cq * 4] = *(const float4*)(B + (size_t)(k0 + kr) * N + cb + cq * 4);
        }
        __syncthreads();
#pragma unroll 8
        for (int k = 0; k < 32; k++) {
            const float4 a = *(const float4*)&As[k][ty * 4];
            const float4 b = *(const float4*)&Bs[k][tx * 4];
            const float av[4] = {a.x, a.y, a.z, a.w};
            const float bv[4] = {b.x, b.y, b.z, b.w};
#pragma unroll
            for (int i = 0; i < 4; i++)
#pragma unroll
                for (int j = 0; j < 4; j++) acc[i][j] += av[i] * bv[j];
        }
    }
#pragma unroll
    for (int i = 0; i < 4; i++) {
        const int r = rb + ty * 4 + i;
#pragma unroll
        for (int j = 0; j < 4; j++) {
            const int cc2 = cb + tx * 4 + j;
            float val = acc[i][j];
            if (mode == 1 || mode == 5) val = (val > 0.f ? val : expf(val) - 1.f) + 1.f;
            if (mode == 2) {
                // v16T[(h*144 + c*9 + l)][n] f16
                const int n = r / 9, l = r - n * 9, hq = cc2 >> 4, cvq = cc2 & 15;
                _Float16* o = (_Float16*)Cv;
                o[((size_t)hq * 144 + cvq * 9 + l) * 2048 + n] = (_Float16)val;
            } else if (mode == 5) {
                // kf16T[col][n] f16
                _Float16* o = (_Float16*)Cv;
                o[(size_t)cc2 * 2048 + r] = (_Float16)val;
            } else {
                Cv[(size_t)r * N + cc2] = val;
            }
        }
    }
}

// trig16[kkut][n] (f16) = cos/sin(kappa_kk * pos_n . dir_u); kkut = (kk*25+u)*2 + t
__global__ void trig_k(const float* __restrict__ pos, const float* __restrict__ kappa,
                       const float* __restrict__ cst, _Float16* __restrict__ trig16) {
    const int n = blockIdx.x, t = threadIdx.x;
    if (t >= 200) return;
    const int kq = t / 25, u = t - kq * 25;
    const float* dirs = cst + 954;
    const float ph = kappa[kq] * (pos[n * 3] * dirs[u * 3] + pos[n * 3 + 1] * dirs[u * 3 + 1] + pos[n * 3 + 2] * dirs[u * 3 + 2]);
    float s, c;
    sincosf(ph, &s, &c);
    const int kkut = (kq * 25 + u) * 2;
    trig16[(size_t)kkut * 2048 + n] = (_Float16)c;
    trig16[(size_t)(kkut + 1) * 2048 + n] = (_Float16)s;
}

// ksum[j] = sum_n kf16T[j][n]; one block per j, coalesced half8 loads
__global__ void ksumT_k(const _Float16* __restrict__ kf16T, float* __restrict__ ksum) {
    const int j = blockIdx.x, t = threadIdx.x;   // 256 threads
    const half8 v = *(const half8*)(kf16T + (size_t)j * 2048 + t * 8);
    float s = 0.f;
#pragma unroll
    for (int i = 0; i < 8; i++) s += (float)v[i];
#pragma unroll
    for (int off = 32; off > 0; off >>= 1) s += __shfl_down(s, off, 64);
    __shared__ float red[4];
    if ((t & 63) == 0) red[t >> 6] = s;
    __syncthreads();
    if (t == 0) ksum[j] = red[0] + red[1] + red[2] + red[3];
}

// rz[n][h] = 1 / (qf[n,h,:].ksum[h,:] + 1e-6)
__global__ void z_k(const float* __restrict__ qf, const float* __restrict__ ksum, float* __restrict__ rz) {
    const int idx = blockIdx.x * 256 + threadIdx.x;   // N*H = 16384
    const int n = idx >> 3, h = idx & 7;
    float s = 0.f;
#pragma unroll
    for (int d = 0; d < 32; d++) s += qf[(size_t)n * 256 + h * 32 + d] * ksum[h * 32 + d];
    rz[idx] = 1.0f / (s + 1e-6f);
}

// G[kk][h][u][l*9+m] = sum_e aE[e,h,kk] * YW[e,u] * RRED[e,l,m]
__global__ void g_k(const float* __restrict__ a, const float* __restrict__ cst, float* __restrict__ G) {
    const int kk = blockIdx.x & 7, h = blockIdx.x >> 3;
    __shared__ float ae[9];
    if (threadIdx.x < 9) {
        const int ldeg[9] = {0, 1, 1, 1, 2, 2, 2, 2, 2};
        ae[threadIdx.x] = a[ldeg[threadIdx.x] * 64 + h * 8 + kk];
    }
    __syncthreads();
    const float* yw = cst;
    const float* rred = cst + 225;
    for (int i = threadIdx.x; i < 25 * 81; i += 256) {
        const int u = i / 81, lm = i - u * 81;
        float s = 0.f;
#pragma unroll
        for (int e = 0; e < 9; e++) s += ae[e] * yw[e * 25 + u] * rred[e * 81 + lm];
        G[((size_t)(kk * 8 + h) * 25 + u) * 81 + lm] = s;
    }
}

// MFMA multipole, barrier-free / LDS-free:
//   M16[kkut][h][cl*32+d] = sum_n trig16[kkut][n] * kf16T[h*32+d][n] * v16T[h*144+cl][n]
// B-fragments built in registers: W[col][n] = kf16 ⊙ v16 (both n-contiguous).
// grid (36 cl-quads, 4 row-blocks, 8 h); block 256 = 4 waves;
// wave: 32 rows (2 row-tiles) x 128 cols (4 cl x 32 d = 8 subtiles)
__global__ __launch_bounds__(256) void multipole_mm_k(const _Float16* __restrict__ trig16,
                                                      const _Float16* __restrict__ kf16T,
                                                      const _Float16* __restrict__ v16T,
                                                      _Float16* __restrict__ M16) {
    const int cl0 = blockIdx.x * 4;          // 4 cl per block -> 128 cols
    const int cb  = blockIdx.x * 128;
    const int rb  = blockIdx.y * 128;        // rows (kkut, padded to 512)
    const int h   = blockIdx.z;
    const int tid = threadIdx.x;
    const int w = tid >> 6, lane = tid & 63;
    const int l15 = lane & 15, quad = lane >> 4;

    const int r0 = rb + w * 32;

    float4v acc[2][8];
#pragma unroll
    for (int rt = 0; rt < 2; rt++)
#pragma unroll
        for (int s = 0; s < 8; s++) acc[rt][s] = float4v{0.f, 0.f, 0.f, 0.f};

    const _Float16* kfp = kf16T + ((size_t)h * 32) * 2048 + quad * 8;          // + d*2048 + nb
    const _Float16* vp  = v16T + ((size_t)h * 144 + cl0) * 2048 + quad * 8;    // + c*2048 + nb
    const _Float16* tp  = trig16 + ((size_t)(r0 + l15)) * 2048 + quad * 8;     // + rt*16*2048 + nb

    for (int nb = 0; nb < 2048; nb += 32) {
        const half8 kq0 = *(const half8*)(kfp + (size_t)l15 * 2048 + nb);
        const half8 kq1 = *(const half8*)(kfp + (size_t)(16 + l15) * 2048 + nb);
        half8 vq[4];
#pragma unroll
        for (int c = 0; c < 4; c++) vq[c] = *(const half8*)(vp + (size_t)c * 2048 + nb);
        const half8 af0 = *(const half8*)(tp + nb);
        const half8 af1 = *(const half8*)(tp + 16 * 2048 + nb);
#pragma unroll
        for (int c = 0; c < 4; c++) {
            const half8 b0 = kq0 * vq[c];
            const half8 b1 = kq1 * vq[c];
            acc[0][c * 2 + 0] = __builtin_amdgcn_mfma_f32_16x16x32_f16(af0, b0, acc[0][c * 2 + 0], 0, 0, 0);
            acc[0][c * 2 + 1] = __builtin_amdgcn_mfma_f32_16x16x32_f16(af0, b1, acc[0][c * 2 + 1], 0, 0, 0);
            acc[1][c * 2 + 0] = __builtin_amdgcn_mfma_f32_16x16x32_f16(af1, b0, acc[1][c * 2 + 0], 0, 0, 0);
            acc[1][c * 2 + 1] = __builtin_amdgcn_mfma_f32_16x16x32_f16(af1, b1, acc[1][c * 2 + 1], 0, 0, 0);
        }
    }
    // epilogue: C fragment (col=lane&15, row=quad*4+reg) -> M16[kkut][h][col]
#pragma unroll
    for (int rt = 0; rt < 2; rt++)
#pragma unroll
        for (int c = 0; c < 4; c++)
#pragma unroll
            for (int half = 0; half < 2; half++)
#pragma unroll
                for (int r = 0; r < 4; r++) {
                    const int row = r0 + rt * 16 + quad * 4 + r;
                    const int col = cb + c * 32 + half * 16 + l15;
                    M16[((size_t)row * 8 + h) * 4608 + col] = (_Float16)acc[rt][c * 2 + half][r];
                }
}

// MG[kkut][h][quad][cm][8j] (f16) = sum_l M16[kkut][h][(c*9+l)*32+d] * G[kk,h,u][l*9+m]
//   cm = c*9+m, d = quad*8+j
__global__ __launch_bounds__(256) void fold_k(const _Float16* __restrict__ Mv, const float* __restrict__ G,
                                              _Float16* __restrict__ MG) {
    const int kt = blockIdx.x, h = blockIdx.y;
    const int tid = threadIdx.x;
    __shared__ float ms[144 * 33];   // [cl][d] padded 33
    __shared__ float gs[81];
    const _Float16* src = Mv + ((size_t)kt * 8 + h) * 4608;
    for (int i = tid; i < 4608; i += 256) {
        const int cl = i >> 5, d = i & 31;
        ms[cl * 33 + d] = (float)src[i];
    }
    const int kk = kt / 50, u = (kt >> 1) % 25;
    if (tid < 81) gs[tid] = G[(((size_t)kk * 8 + h) * 25 + u) * 81 + tid];
    __syncthreads();
    _Float16* dst = MG + ((size_t)kt * 8 + h) * 4608;
    for (int i = tid; i < 4608; i += 256) {
        const int quad = i / 1152, r = i - quad * 1152;
        const int cm = r >> 3, j = r & 7;
        const int d = quad * 8 + j, c = cm / 9, m = cm - c * 9;
        float s = 0.f;
#pragma unroll
        for (int l = 0; l < 9; l++) s += ms[(c * 9 + l) * 33 + d] * gs[l * 9 + m];
        dst[i] = (_Float16)s;
    }
}

// local stage via MFMA, barrier-free: B-fragments are direct b128 global loads
// (MG layout == fragment layout); partials stored per kt-slice, no atomics.
// grid (16 ngroups, 8 h, 4 slices); block 256 = 4 waves; wave: 32 n x 144 cm
__global__ __launch_bounds__(256) void mm_local_k(const float* __restrict__ qf, const _Float16* __restrict__ trig16,
                                                  const _Float16* __restrict__ MG, float* __restrict__ outp) {
    const int h = blockIdx.y;
    const int n0 = blockIdx.x * 128;
    const int slice = blockIdx.z;
    const int tid = threadIdx.x;
    const int w = tid >> 6, lane = tid & 63;
    const int l15 = lane & 15, quad = lane >> 4;

    const int nbase = n0 + w * 32;
    float qfr[2][8];
#pragma unroll
    for (int rt = 0; rt < 2; rt++) {
        const int n = nbase + rt * 16 + l15;
        const float* qp = qf + (size_t)n * 256 + h * 32 + quad * 8;
#pragma unroll
        for (int j = 0; j < 8; j++) qfr[rt][j] = qp[j];
    }
    float4v acc[2][9];
#pragma unroll
    for (int rt = 0; rt < 2; rt++)
#pragma unroll
        for (int ct = 0; ct < 9; ct++) acc[rt][ct] = float4v{0.f, 0.f, 0.f, 0.f};

    const int kt0 = slice * 100;
    const _Float16* slab0 = MG + (((size_t)kt0 * 8 + h) * 4608) + quad * 1152 + l15 * 8;
    const _Float16* trg0  = trig16 + (size_t)kt0 * 2048 + nbase + l15;

    for (int kt = 0; kt < 100; kt++) {
        const _Float16* slab = slab0 + (size_t)kt * 8 * 4608;
        // A fragments: trig[kkut][n] * qf[n][d],  d = quad*8+j
        const float tv0 = (float)trg0[(size_t)kt * 2048];
        const float tv1 = (float)trg0[(size_t)kt * 2048 + 16];
        half8 af[2];
#pragma unroll
        for (int j = 0; j < 8; j++) af[0][j] = (_Float16)(tv0 * qfr[0][j]);
#pragma unroll
        for (int j = 0; j < 8; j++) af[1][j] = (_Float16)(tv1 * qfr[1][j]);
#pragma unroll
        for (int ct = 0; ct < 9; ct++) {
            const half8 b = *(const half8*)(slab + ct * 128);
            acc[0][ct] = __builtin_amdgcn_mfma_f32_16x16x32_f16(af[0], b, acc[0][ct], 0, 0, 0);
            acc[1][ct] = __builtin_amdgcn_mfma_f32_16x16x32_f16(af[1], b, acc[1][ct], 0, 0, 0);
        }
    }
    // epilogue: direct stores into this slice's partial buffer outp[slice][n][m][h][c]
    float* dst = outp + (size_t)slice * 2359296;
#pragma unroll
    for (int rt = 0; rt < 2; rt++)
#pragma unroll
        for (int ct = 0; ct < 9; ct++) {
#pragma unroll
            for (int r = 0; r < 4; r++) {
                const int n = nbase + rt * 16 + quad * 4 + r;
                const int cm = ct * 16 + l15;
                const int c = cm / 9, m = cm - c * 9;
                dst[((size_t)n * 9 + m) * 128 + h * 16 + c] = acc[rt][ct][r];
            }
        }
}

// ================================ launcher =================================
extern "C" void kernel_launch(void* const* d_in, const int* in_sizes, int n_in,
                              void* d_out, int out_size, void* d_ws, size_t ws_size,
                              hipStream_t stream) {
    const float* pos  = (const float*)d_in[0];
    const float* feat = (const float*)d_in[1];
    const float* Wq   = (const float*)d_in[2];
    const float* Wk   = (const float*)d_in[3];
    const float* Wv   = (const float*)d_in[4];
    const float* Wo   = (const float*)d_in[5];
    const float* a    = (const float*)d_in[6];
    const float* kap  = (const float*)d_in[7];
    float* out = (float*)d_out;
    float* ws = (float*)d_ws;

    // float-slot layout (~77.8 MB total)
    float* qf    = ws;                    // 524288
    float* kfTF  = qf + 524288;           // 262144 slots = kf16T f16[256*2048]
    float* vTF   = kfTF + 262144;         // 1179648 slots = v16T f16[1152*2048]
    float* trigF = vTF + 1179648;         // 524288 slots = trig16 f16[512*2048]
    float* ksum  = trigF + 524288;        // 256
    float* rz    = ksum + 256;            // 16384
    float* G     = rz + 16384;            // 129600
    float* M16F  = G + 129600;            // 9437184 slots = M16 f16[512*8*4608]; later outp[4][2359296]
    float* regX  = M16F + 9437184;        // 7372800 slots: R (first 1572864), later MG f16[400*8*4608]
    float* R     = regX;
    float* outp  = M16F;                  // overlay: M16 dead after fold_k; 4 partial buffers
    _Float16* trig16 = (_Float16*)trigF;
    _Float16* kf16T  = (_Float16*)kfTF;
    _Float16* v16T   = (_Float16*)vTF;
    _Float16* M16    = (_Float16*)M16F;
    _Float16* MG16   = (_Float16*)regX;

    const float* cst = d_const_g;

    hipLaunchKernelGGL(radial_k, dim3(2048), dim3(256), 0, stream, feat, R);
    hipLaunchKernelGGL(gemm_k, dim3(4, 32), dim3(256), 0, stream, R, Wq, qf, 2048, 256, 768, 1, rz);
    hipLaunchKernelGGL(gemm_k, dim3(4, 32), dim3(256), 0, stream, R, Wk, kfTF, 2048, 256, 768, 5, rz);
    hipLaunchKernelGGL(gemm_k, dim3(2, 288), dim3(256), 0, stream, feat, Wv, vTF, 18432, 128, 256, 2, rz);
    hipMemsetAsync(trigF, 0, 524288 * sizeof(float), stream);   // zero pad rows 400..511
    hipLaunchKernelGGL(trig_k, dim3(2048), dim3(256), 0, stream, pos, kap, cst, trig16);
    hipLaunchKernelGGL(ksumT_k, dim3(256), dim3(256), 0, stream, kf16T, ksum);
    hipLaunchKernelGGL(z_k, dim3(64), dim3(256), 0, stream, qf, ksum, rz);
    hipLaunchKernelGGL(g_k, dim3(64), dim3(256), 0, stream, a, cst, G);
    hipLaunchKernelGGL(multipole_mm_k, dim3(36, 4, 8), dim3(256), 0, stream, trig16, kf16T, v16T, M16);
    hipLaunchKernelGGL(fold_k, dim3(400, 8), dim3(256), 0, stream, M16, G, MG16);
    hipLaunchKernelGGL(mm_local_k, dim3(16, 8, 4), dim3(256), 0, stream, qf, trig16, MG16, outp);
    hipLaunchKernelGGL(gemm_k, dim3(4, 288), dim3(256), 0, stream, outp, Wo, out, 18432, 256, 128, 4, rz);
}